// Round 13
// baseline (902.131 us; speedup 1.0000x reference)
//
#include <hip/hip_runtime.h>
#include <hip/hip_bf16.h>
#include <stdint.h>

#define NND 12000
#define DM  256
#define KNN 16
#define NB  4096          // x-buckets
#define BW  0.00390625f   // bucket width = 1/256 over [-8, 8)
#define NPB 32            // nodes per block (sorted positions)
#define G   8             // threads per node
#define PAD 352           // phase-A staging pad (positions per side)
#define STG (NPB + 2*PAD) // 736 staged points max
#define CH  256           // phase-B chunk size
#define CAP 6             // max chunks per side
#define LSTR 138          // u64 stride per node in lists region (8*17+2)

// Opaque register barrier: prevents FMA contraction (r9: made knn bit-match numpy
// -> absmax 0.0. DO NOT REMOVE).
#define FPBAR(x) asm volatile("" : "+v"(x))

typedef unsigned long long u64;

__device__ __forceinline__ float geluf(float x){ return 0.5f*x*(1.0f + erff(x*0.70710678118654752f)); }
__device__ __forceinline__ int bucketof(float x){
  int b = (int)floorf((x + 8.0f) * 256.0f);
  return min(max(b, 0), NB-1);
}

// bit-exact numpy distance key (r9-verified). Low 32 bits = original node idx.
__device__ __forceinline__ u64 make_key(float xi, float yi, float sqi,
                                        float cx, float cy, int jd, int self){
  float ax = cx*cx;  FPBAR(ax);
  float ay = cy*cy;  FPBAR(ay);
  float sqj = ax + ay;   FPBAR(sqj);
  float px = xi*cx;    FPBAR(px);
  float py = yi*cy;    FPBAR(py);
  float dt = px + py;    FPBAR(dt);            // NO-FMA dot
  float two_dt = 2.0f*dt;  FPBAR(two_dt);
  float ss = sqi + sqj;    FPBAR(ss);
  float d2 = ss - two_dt;  FPBAR(d2);
  float dist = __fsqrt_rn(fmaxf(d2, 0.0f));
  u64 key = ((u64)__float_as_uint(dist) << 32) | (unsigned)jd;
  return (jd == self) ? ~0ULL : key;
}

// branchless sorted top-16 insert (ascending u64 keys)
__device__ __forceinline__ void ladder_insert(u64* L, u64 key){
  bool c[KNN];
  #pragma unroll
  for (int t=0;t<KNN;t++) c[t] = key < L[t];
  #pragma unroll
  for (int t=KNN-1;t>=1;t--) L[t] = c[t-1] ? L[t-1] : (c[t] ? key : L[t]);
  L[0] = c[0] ? key : L[0];
}

// 8-way merge of sorted 16-lists (disjoint keys) -> ascending out16
__device__ __forceinline__ void merge8(const u64* nb, u64* out16){
  u64 h[G]; int p[G];
  #pragma unroll
  for (int l=0;l<G;l++){ p[l]=1; h[l]=nb[l*17]; }
  #pragma unroll
  for (int r=0;r<KNN;r++){
    u64 m=h[0]; int lm=0;
    #pragma unroll
    for (int l=1;l<G;l++) if (h[l]<m){ m=h[l]; lm=l; }
    out16[r]=m;
    #pragma unroll
    for (int l=0;l<G;l++) if (l==lm){ h[l] = (p[l]<KNN) ? nb[l*17+p[l]] : ~0ULL; p[l]++; }
  }
}

// ---------------- dtype detection (proven: picks f32 here) ----------------
__global__ __launch_bounds__(256) void detect_kernel_r13(
    const unsigned* __restrict__ a, int na,
    const unsigned* __restrict__ b, int nb, int* __restrict__ flag)
{
  __shared__ int cnt;
  if (threadIdx.x == 0) cnt = 0;
  __syncthreads();
  int c = 0;
  for (int i = threadIdx.x; i < na; i += 256){
    int ex = (a[i] >> 7) & 0xFF;
    c += (ex >= 113 && ex <= 131) ? 1 : 0;
  }
  for (int i = threadIdx.x; i < nb; i += 256){
    int ex = (b[i] >> 7) & 0xFF;
    c += (ex >= 113 && ex <= 131) ? 1 : 0;
  }
  atomicAdd(&cnt, c);
  __syncthreads();
  if (threadIdx.x == 0) *flag = (cnt > (na + nb) / 2) ? 1 : 0;
}

// ---------------- decode all inputs to f32 workspace ----------------
struct SegTable {
  const void* src[16];
  float*      dst[16];
  int         cnt[16];
  int         total;
};

__global__ __launch_bounds__(256) void decode_kernel_r13(SegTable t, const int* __restrict__ flag)
{
  const int is_bf16 = *flag;
  for (int e = blockIdx.x*256 + threadIdx.x; e < t.total; e += gridDim.x*256){
    int rem = e, s = 0;
    while (rem >= t.cnt[s]){ rem -= t.cnt[s]; ++s; }
    float v;
    if (is_bf16) v = __uint_as_float(((unsigned)((const unsigned short*)t.src[s])[rem]) << 16);
    else         v = ((const float*)t.src[s])[rem];
    t.dst[s][rem] = v;
  }
}

// ---------------- bucket pre-pass ----------------
__global__ __launch_bounds__(256) void zero_kernel_r13(int* __restrict__ hist, int* __restrict__ cursor,
                                                       int* __restrict__ ocnt)
{
  int t = blockIdx.x*256 + threadIdx.x;
  if (t < NB){ hist[t] = 0; cursor[t] = 0; }
  if (blockIdx.x == 0 && threadIdx.x == 0) *ocnt = 0;
}

__global__ __launch_bounds__(256) void count_kernel_r13(const float* __restrict__ cents,
                                                        int* __restrict__ hist)
{
  int i = blockIdx.x*256 + threadIdx.x;
  if (i < NND) atomicAdd(&hist[bucketof(cents[2*i])], 1);
}

__global__ __launch_bounds__(1024) void scan_kernel_r13(const int* __restrict__ hist,
                                                        int* __restrict__ offs)
{
  __shared__ int s[1024];
  int t = threadIdx.x;
  int h0 = hist[t*4], h1 = hist[t*4+1], h2 = hist[t*4+2], h3 = hist[t*4+3];
  int tot = h0+h1+h2+h3;
  s[t] = tot;
  __syncthreads();
  for (int d=1; d<1024; d<<=1){
    int v = (t >= d) ? s[t-d] : 0;
    __syncthreads();
    s[t] += v;
    __syncthreads();
  }
  int excl = s[t] - tot;
  offs[t*4]   = excl;
  offs[t*4+1] = excl + h0;
  offs[t*4+2] = excl + h0 + h1;
  offs[t*4+3] = excl + h0 + h1 + h2;
}

__global__ __launch_bounds__(256) void scatter_kernel_r13(const float* __restrict__ cents,
    const int* __restrict__ offs, int* __restrict__ cursor,
    float2* __restrict__ sxy, int* __restrict__ sid)
{
  int i = blockIdx.x*256 + threadIdx.x;
  if (i < NND){
    float x = cents[2*i], y = cents[2*i+1];
    int b = bucketof(x);
    int pos = offs[b] + atomicAdd(&cursor[b], 1);
    sxy[pos] = make_float2(x, y);
    sid[pos] = i;
  }
}

// ---------------- kNN tile kernel: 32 sorted nodes/block, 8 threads/node ----------------
__global__ __launch_bounds__(256) void knn_tile_r13(
    const float2* __restrict__ sxy, const int* __restrict__ sid,
    int* __restrict__ idx_out, float* __restrict__ w_out,
    int* __restrict__ ocnt, int* __restrict__ olist)
{
  __shared__ float2 s_xy[STG];
  __shared__ int    s_id[STG];
  __shared__ float2 c_xy[CH];
  __shared__ int    c_id[CH];
  __shared__ u64    lists[NPB*LSTR];
  __shared__ float  sh_xL, sh_xR;
  __shared__ int    sh_anyL, sh_anyR;

  const int tid = threadIdx.x;
  const int node_local = tid >> 3;        // 0..31
  const int g = tid & 7;                  // 0..7
  const int lane = tid & 63;
  const int s0 = blockIdx.x * NPB;

  // phase-A staging
  const int qlo0 = max(s0 - PAD, 0);
  const int qhi0 = min(s0 + NPB + PAD, NND);
  const int S = qhi0 - qlo0;
  for (int k = tid; k < S; k += 256){
    float2 v = sxy[qlo0 + k];
    s_xy[k] = v;
    s_id[k] = sid[qlo0 + k];
    if (k == 0)   sh_xL = v.x;
    if (k == S-1) sh_xR = v.x;
  }
  __syncthreads();

  // own node data (from LDS)
  const int q_own = (s0 + node_local) - qlo0;
  const float xi = s_xy[q_own].x;
  const float yi = s_xy[q_own].y;
  const int   own = s_id[q_own];
  float sx = xi*xi; FPBAR(sx);
  float sy = yi*yi; FPBAR(sy);
  float sqi = sx + sy; FPBAR(sqi);

  u64 L[KNN];
  #pragma unroll
  for (int t=0;t<KNN;t++) L[t] = ~0ULL;

  // phase A scan: stride-8 over staged points (LDS broadcast-friendly)
  for (int q = g; q < S; q += G){
    float2 cu = s_xy[q];
    u64 key = make_key(xi, yi, sqi, cu.x, cu.y, s_id[q], own);
    ladder_insert(L, key);
  }

  // dump lists, exact B = 16th of staged union
  u64* nb = &lists[node_local * LSTR];
  #pragma unroll
  for (int t=0;t<KNN;t++) nb[g*17 + t] = L[t];
  __syncthreads();
  float Bv = 0.f;
  if (g == 0){
    u64 o16[KNN];
    merge8(nb, o16);
    Bv = __uint_as_float((unsigned)(o16[KNN-1] >> 32));
  }
  float B = __shfl(Bv, lane & 56, 64);
  const float thr = B*B + 2e-4f;

  int qlo = qlo0, qhi = qhi0;

  // phase B: chunked extension with fixed exact bound
  for (int it = 0; it < CAP; ++it){
    float dxl = xi - ((float)(bucketof(sh_xL)+1)*BW - 8.0f);
    float dxr = ((float)bucketof(sh_xR)*BW - 8.0f) - xi;
    bool needL = (qlo > 0)   && !((dxl > 0.0f) && (dxl*dxl > thr));
    bool needR = (qhi < NND) && !((dxr > 0.0f) && (dxr*dxr > thr));
    if (tid == 0){ sh_anyL = 0; sh_anyR = 0; }
    __syncthreads();
    if (g == 0){ if (needL) atomicOr(&sh_anyL, 1); if (needR) atomicOr(&sh_anyR, 1); }
    __syncthreads();
    int aL = sh_anyL, aR = sh_anyR;
    if (!aL && !aR) break;
    if (aL){
      int nql = max(qlo - CH, 0);
      int cl = qlo - nql;
      for (int k = tid; k < cl; k += 256){
        float2 v = sxy[nql + k];
        c_xy[k] = v; c_id[k] = sid[nql + k];
        if (k == 0) sh_xL = v.x;
      }
      __syncthreads();
      if (needL){
        for (int q = g; q < cl; q += G){
          float2 cu = c_xy[q];
          ladder_insert(L, make_key(xi, yi, sqi, cu.x, cu.y, c_id[q], own));
        }
      }
      qlo = nql;
      __syncthreads();
    }
    if (aR){
      int cr = min(NND - qhi, CH);
      for (int k = tid; k < cr; k += 256){
        float2 v = sxy[qhi + k];
        c_xy[k] = v; c_id[k] = sid[qhi + k];
        if (k == cr-1) sh_xR = v.x;
      }
      __syncthreads();
      if (needR){
        for (int q = g; q < cr; q += G){
          float2 cu = c_xy[q];
          ladder_insert(L, make_key(xi, yi, sqi, cu.x, cu.y, c_id[q], own));
        }
      }
      qhi += cr;
      __syncthreads();
    }
  }

  // outlier registration (rare: large-d16 density outliers)
  {
    float dxl = xi - ((float)(bucketof(sh_xL)+1)*BW - 8.0f);
    float dxr = ((float)bucketof(sh_xR)*BW - 8.0f) - xi;
    bool needL = (qlo > 0)   && !((dxl > 0.0f) && (dxl*dxl > thr));
    bool needR = (qhi < NND) && !((dxr > 0.0f) && (dxr*dxr > thr));
    if (g == 0 && (needL || needR)){
      int s = atomicAdd(ocnt, 1);
      olist[s] = own;
    }
  }

  // re-dump (lists may have changed in phase B), final merge + outputs
  __syncthreads();
  #pragma unroll
  for (int t=0;t<KNN;t++) nb[g*17 + t] = L[t];
  __syncthreads();
  if (g == 0){
    u64 o16[KNN];
    merge8(nb, o16);
    #pragma unroll
    for (int t=0;t<KNN;t++) idx_out[(size_t)own*KNN + t] = (int)(unsigned)(o16[t] & 0xFFFFFFFFull);
    float inv[KNN];
    #pragma unroll
    for (int t=0;t<KNN;t++){
      float d = __uint_as_float((unsigned)(o16[t] >> 32));
      inv[t] = __fdiv_rn(1.0f, fmaxf(d, 1e-4f));
    }
    float r8v[8];
    #pragma unroll
    for (int t=0;t<8;t++){ r8v[t] = inv[t] + inv[t+8]; FPBAR(r8v[t]); }
    float s01 = r8v[0]+r8v[1]; FPBAR(s01);
    float s23 = r8v[2]+r8v[3]; FPBAR(s23);
    float s45 = r8v[4]+r8v[5]; FPBAR(s45);
    float s67 = r8v[6]+r8v[7]; FPBAR(s67);
    float sA = s01+s23; FPBAR(sA);
    float sB = s45+s67; FPBAR(sB);
    float s = sA + sB;
    s = fmaxf(s, 1e-8f);
    #pragma unroll
    for (int t=0;t<KNN;t++) w_out[(size_t)own*KNN + t] = __fdiv_rn(inv[t], s);
  }
}

// ---------------- brute-force fallback for outlier nodes (r10 body, bit-exact) ----------------
__global__ __launch_bounds__(256) void knn_brute_r13(const float* __restrict__ cents,
    const int* __restrict__ olist, const int* __restrict__ ocnt,
    int* __restrict__ idx_out, float* __restrict__ w_out)
{
  __shared__ u64 s_k[KNN*256];
  __shared__ u64 bk[4]; __shared__ int bt[4];
  __shared__ u64 out_k[KNN];
  __shared__ int s_win;

  const int tid = threadIdx.x;
  const int cnt = *ocnt;
  for (int slot = blockIdx.x; slot < cnt; slot += gridDim.x){
    const int i = olist[slot];
    const float cx = cents[2*i];
    const float cy = cents[2*i+1];
    float sx = cx*cx;  FPBAR(sx);
    float sy = cy*cy;  FPBAR(sy);
    float sqi = sx + sy;  FPBAR(sqi);

    u64 L[KNN];
    #pragma unroll
    for (int t=0;t<KNN;t++) L[t] = ~0ULL;

    for (int j=tid; j<NND; j+=256){
      float2 cu = *(const float2*)(cents + 2*j);
      ladder_insert(L, make_key(cx, cy, sqi, cu.x, cu.y, j, i));
    }
    #pragma unroll
    for (int t=0;t<KNN;t++) s_k[t*256+tid] = L[t];
    __syncthreads();

    int p = 0;
    const int lane = tid & 63, wid = tid >> 6;
    for (int r=0;r<KNN;r++){
      u64 ck = s_k[p*256+tid]; int ct = tid;
      #pragma unroll
      for (int off=32; off>0; off>>=1){
        u64 ok = __shfl_down(ck, off, 64);
        int ot = __shfl_down(ct, off, 64);
        if (ok < ck){ ck = ok; ct = ot; }
      }
      if (lane == 0){ bk[wid]=ck; bt[wid]=ct; }
      __syncthreads();
      if (tid == 0){
        u64 mk=bk[0]; int mt=bt[0];
        for (int qq=1;qq<4;qq++) if (bk[qq] < mk){ mk=bk[qq]; mt=bt[qq]; }
        out_k[r]=mk; s_win=mt;
      }
      __syncthreads();
      if (tid == s_win) ++p;
      __syncthreads();
    }
    if (tid < KNN) idx_out[(size_t)i*KNN + tid] = (int)(unsigned)(out_k[tid] & 0xFFFFFFFFull);
    if (tid == 0){
      float inv[KNN];
      #pragma unroll
      for (int t=0;t<KNN;t++){
        float d = __uint_as_float((unsigned)(out_k[t] >> 32));
        inv[t] = __fdiv_rn(1.0f, fmaxf(d, 1e-4f));
      }
      float r8v[8];
      #pragma unroll
      for (int t=0;t<8;t++){ r8v[t] = inv[t] + inv[t+8]; FPBAR(r8v[t]); }
      float s01 = r8v[0]+r8v[1]; FPBAR(s01);
      float s23 = r8v[2]+r8v[3]; FPBAR(s23);
      float s45 = r8v[4]+r8v[5]; FPBAR(s45);
      float s67 = r8v[6]+r8v[7]; FPBAR(s67);
      float sA = s01+s23; FPBAR(sA);
      float sB = s45+s67; FPBAR(sB);
      float s = sA + sB;
      s = fmaxf(s, 1e-8f);
      #pragma unroll
      for (int t=0;t<KNN;t++) w_out[(size_t)i*KNN + t] = __fdiv_rn(inv[t], s);
    }
    __syncthreads();
  }
}

// ---------------- GEMM: C[M,OUT] = gelu(A1@W1^T (+ A2@W2^T) (+ bias)) ----------------
template<int OUT, bool DUAL, bool BIAS>
__global__ __launch_bounds__(256) void mm_kernel_r13(
    const float* __restrict__ A1, const float* __restrict__ A2,
    const float* __restrict__ W1, const float* __restrict__ W2,
    const float* __restrict__ bias, float* __restrict__ C)
{
  constexpr int KC = 16;
  constexpr int TM = 32;
  constexpr int WS = KC + 4;
  constexpr int NQ = OUT / 64;
  __shared__ float Wl1[OUT*WS];
  __shared__ float Wl2[DUAL ? OUT*WS : 1];
  __shared__ float Al1[TM*KC];
  __shared__ float Al2[DUAL ? TM*KC : 1];

  const int tid = threadIdx.x;
  const int cg  = tid & 63;
  const int rg  = tid >> 6;
  const int m0  = blockIdx.x * TM;

  float acc[8][NQ];
  #pragma unroll
  for (int r=0;r<8;r++)
    #pragma unroll
    for (int q=0;q<NQ;q++) acc[r][q] = 0.f;

  for (int c0=0; c0<DM; c0+=KC){
    for (int e=tid; e < OUT*(KC/4); e += 256){
      int row = e >> 2;
      int c4  = (e & 3)*4;
      *(float4*)&Wl1[row*WS + c4] = *(const float4*)(W1 + (size_t)row*DM + c0 + c4);
      if (DUAL)
        *(float4*)&Wl2[row*WS + c4] = *(const float4*)(W2 + (size_t)row*DM + c0 + c4);
    }
    for (int e=tid; e < TM*(KC/4); e += 256){
      int row = e >> 2;
      int c4  = (e & 3)*4;
      size_t gi = (size_t)(m0+row)*DM + c0 + c4;
      *(float4*)&Al1[row*KC+c4] = *(const float4*)(A1 + gi);
      if (DUAL) *(float4*)&Al2[row*KC+c4] = *(const float4*)(A2 + gi);
    }
    __syncthreads();
    #pragma unroll
    for (int k4=0; k4<KC/4; k4++){
      float4 wv1[NQ]; float4 wv2[NQ];
      #pragma unroll
      for (int q=0;q<NQ;q++){
        wv1[q] = *(const float4*)&Wl1[(cg+64*q)*WS + k4*4];
        if (DUAL) wv2[q] = *(const float4*)&Wl2[(cg+64*q)*WS + k4*4];
      }
      #pragma unroll
      for (int r=0;r<8;r++){
        float4 a1 = *(const float4*)&Al1[(rg*8+r)*KC + k4*4];
        float4 a2;
        if (DUAL) a2 = *(const float4*)&Al2[(rg*8+r)*KC + k4*4];
        #pragma unroll
        for (int q=0;q<NQ;q++){
          float s = acc[r][q];
          s = fmaf(a1.x, wv1[q].x, s);
          s = fmaf(a1.y, wv1[q].y, s);
          s = fmaf(a1.z, wv1[q].z, s);
          s = fmaf(a1.w, wv1[q].w, s);
          if (DUAL){
            s = fmaf(a2.x, wv2[q].x, s);
            s = fmaf(a2.y, wv2[q].y, s);
            s = fmaf(a2.z, wv2[q].z, s);
            s = fmaf(a2.w, wv2[q].w, s);
          }
          acc[r][q] = s;
        }
      }
    }
    __syncthreads();
  }
  #pragma unroll
  for (int q=0;q<NQ;q++){
    int d = cg + 64*q;
    float bv = BIAS ? bias[d] : 0.f;
    #pragma unroll
    for (int r=0;r<8;r++){
      float v = geluf(acc[r][q] + bv);
      C[(size_t)(m0 + rg*8 + r)*OUT + d] = v;
    }
  }
}

// ---------------- weighted neighbor aggregation ----------------
__global__ __launch_bounds__(256) void agg_kernel_r13(const float* __restrict__ h,
    const int* __restrict__ idx, const float* __restrict__ w, float* __restrict__ agg)
{
  const int lane = threadIdx.x & 63, wid = threadIdx.x >> 6;
  const int n = blockIdx.x*4 + wid;
  const int base = n*KNN;
  float4 acc = make_float4(0.f,0.f,0.f,0.f);
  for (int k=0;k<KNN;k++){
    int j = idx[base+k];
    float wk = w[base+k];
    float4 hv = *(const float4*)(h + (size_t)j*DM + lane*4);
    acc.x = fmaf(wk, hv.x, acc.x);
    acc.y = fmaf(wk, hv.y, acc.y);
    acc.z = fmaf(wk, hv.z, acc.z);
    acc.w = fmaf(wk, hv.w, acc.w);
  }
  *(float4*)(agg + (size_t)n*DM + lane*4) = acc;
}

// ---------------- h = h + layernorm(tmp)*g + b ----------------
__global__ __launch_bounds__(256) void ln_res_kernel_r13(float* __restrict__ h,
    const float* __restrict__ tmp, const float* __restrict__ g, const float* __restrict__ b)
{
  const int lane = threadIdx.x & 63, wid = threadIdx.x >> 6;
  const int n = blockIdx.x*4 + wid;
  float4 x = *(const float4*)(tmp + (size_t)n*DM + lane*4);
  float s = (x.x + x.y) + (x.z + x.w);
  #pragma unroll
  for (int off=32; off>0; off>>=1) s += __shfl_xor(s, off, 64);
  float mu = s * (1.0f/DM);
  float dx0 = x.x-mu, dx1 = x.y-mu, dx2 = x.z-mu, dx3 = x.w-mu;
  float v = (dx0*dx0 + dx1*dx1) + (dx2*dx2 + dx3*dx3);
  #pragma unroll
  for (int off=32; off>0; off>>=1) v += __shfl_xor(v, off, 64);
  float rs = 1.0f / sqrtf(v * (1.0f/DM) + 1e-5f);
  int c = lane*4;
  float4 gv = *(const float4*)(g + c);
  float4 bv = *(const float4*)(b + c);
  float4 hv = *(const float4*)(h + (size_t)n*DM + c);
  hv.x += dx0*rs*gv.x + bv.x;
  hv.y += dx1*rs*gv.y + bv.y;
  hv.z += dx2*rs*gv.z + bv.z;
  hv.w += dx3*rs*gv.w + bv.w;
  *(float4*)(h + (size_t)n*DM + c) = hv;
}

// ---------------- final: out[n] = sigmoid(dot(hid[n], w2) + b2), dtype per flag ----------------
__global__ __launch_bounds__(256) void cls2_kernel_r13(const float* __restrict__ hid,
    const float* __restrict__ w2, const float* __restrict__ b2,
    void* __restrict__ out, const int* __restrict__ flag)
{
  const int lane = threadIdx.x & 63, wid = threadIdx.x >> 6;
  const int n = blockIdx.x*4 + wid;
  float a = hid[(size_t)n*128 + lane]      * w2[lane]
          + hid[(size_t)n*128 + 64 + lane] * w2[64+lane];
  #pragma unroll
  for (int off=32; off>0; off>>=1) a += __shfl_xor(a, off, 64);
  if (lane == 0){
    float v = 1.0f / (1.0f + expf(-(a + b2[0])));
    if (*flag) ((__hip_bfloat16*)out)[n] = __float2bfloat16(v);
    else       ((float*)out)[n] = v;
  }
}

extern "C" void kernel_launch(void* const* d_in, const int* in_sizes, int n_in,
                              void* d_out, int out_size, void* d_ws, size_t ws_size,
                              hipStream_t stream)
{
  // ---- workspace layout (~44.9 MB), fully rewritten every call ----
  char* base = (char*)d_ws;
  int*   flag = (int*)base;                                   // 16 B slot
  float* wreg = (float*)(base + 16);
  static const int sizes[16] = {
    NND*256, NND*2, 256*256, 256, 256*256, 256*256, 256, 256,
    256*256, 256*256, 256, 256, 128*256, 128, 128, 1
  };
  float* ptrs[16];
  {
    float* p = wreg;
    for (int i = 2; i < 16; i++){ ptrs[i] = p; p += sizes[i]; }
    ptrs[1] = p;                          // cents  [24,000]
    p += NND*2;
    ptrs[0] = p;                          // feats  [3,072,000]  (reused as tmp later)
  }
  float* F    = ptrs[0];
  float* C    = ptrs[1];
  float* h    = F + (size_t)NND*DM;
  float* agg  = h + (size_t)NND*DM;
  float* hid  = agg + (size_t)NND*DM;
  int*  gidx  = (int*)(hid + (size_t)NND*128);
  float* gw   = (float*)(gidx + (size_t)NND*KNN);
  // knn pre-pass scratch
  float2* sxy   = (float2*)(gw + (size_t)NND*KNN);
  int*    sid   = (int*)(sxy + NND);
  int*    hist  = sid + NND;
  int*    cursor= hist + NB;
  int*    offs  = cursor + NB;
  int*    ocnt  = offs + NB;
  int*    olist = ocnt + 1;               // up to 12000 ints

  // ---- dtype detect + decode ----
  detect_kernel_r13<<<1, 256, 0, stream>>>((const unsigned*)d_in[1], 4096,
                                           (const unsigned*)d_in[0], 16384, flag);
  SegTable t;
  int total = 0;
  for (int i = 0; i < 16; i++){
    t.src[i] = d_in[i];
    t.dst[i] = ptrs[i];
    t.cnt[i] = sizes[i];
    total += sizes[i];
  }
  t.total = total;
  decode_kernel_r13<<<(total + 255)/256, 256, 0, stream>>>(t, flag);

  const float* enc_w  = ptrs[2];  const float* enc_b  = ptrs[3];
  const float* g1_ws  = ptrs[4];  const float* g1_wn  = ptrs[5];
  const float* g1_g   = ptrs[6];  const float* g1_b   = ptrs[7];
  const float* g2_ws  = ptrs[8];  const float* g2_wn  = ptrs[9];
  const float* g2_g   = ptrs[10]; const float* g2_b   = ptrs[11];
  const float* cls_w1 = ptrs[12]; const float* cls_b1 = ptrs[13];
  const float* cls_w2 = ptrs[14]; const float* cls_b2 = ptrs[15];

  dim3 b256(256);
  // knn pre-pass: bucket counting sort by x (+ zero outlier counter)
  zero_kernel_r13<<<(NB + 255)/256, b256, 0, stream>>>(hist, cursor, ocnt);
  count_kernel_r13<<<(NND + 255)/256, b256, 0, stream>>>(C, hist);
  scan_kernel_r13<<<1, 1024, 0, stream>>>(hist, offs);
  scatter_kernel_r13<<<(NND + 255)/256, b256, 0, stream>>>(C, offs, cursor, sxy, sid);
  // encoder: h = gelu(feats @ enc_w^T + enc_b)
  mm_kernel_r13<256,false,true><<<NND/32, b256, 0, stream>>>(F, nullptr, enc_w, nullptr, enc_b, h);
  // knn: tile kernel + brute fallback for outliers
  knn_tile_r13<<<NND/NPB, b256, 0, stream>>>(sxy, sid, gidx, gw, ocnt, olist);
  knn_brute_r13<<<64, b256, 0, stream>>>(C, olist, ocnt, gidx, gw);
  // sage layer 1 (tmp := F, feats dead after encoder)
  agg_kernel_r13<<<NND/4, b256, 0, stream>>>(h, gidx, gw, agg);
  mm_kernel_r13<256,true,false><<<NND/32, b256, 0, stream>>>(h, agg, g1_ws, g1_wn, nullptr, F);
  ln_res_kernel_r13<<<NND/4, b256, 0, stream>>>(h, F, g1_g, g1_b);
  // sage layer 2
  agg_kernel_r13<<<NND/4, b256, 0, stream>>>(h, gidx, gw, agg);
  mm_kernel_r13<256,true,false><<<NND/32, b256, 0, stream>>>(h, agg, g2_ws, g2_wn, nullptr, F);
  ln_res_kernel_r13<<<NND/4, b256, 0, stream>>>(h, F, g2_g, g2_b);
  // classifier
  mm_kernel_r13<128,false,true><<<NND/32, b256, 0, stream>>>(h, nullptr, cls_w1, nullptr, cls_b1, hid);
  cls2_kernel_r13<<<NND/4, b256, 0, stream>>>(hid, cls_w2, cls_b2, d_out, flag);
}

// Round 14
// 639.570 us; speedup vs baseline: 1.4105x; 1.4105x over previous
//
#include <hip/hip_runtime.h>
#include <hip/hip_bf16.h>
#include <stdint.h>

#define NND 12000
#define DM  256
#define KNN 16
#define NB  4096          // x-buckets
#define BW  0.00390625f   // bucket width = 1/256 over [-8, 8)
#define RW  16            // fixed-window rounds (16*64 = 1024 candidates)

// Opaque register barrier: prevents FMA contraction (r9: made knn bit-match numpy
// -> absmax 0.0. DO NOT REMOVE).
#define FPBAR(x) asm volatile("" : "+v"(x))

typedef unsigned long long u64;

__device__ __forceinline__ float geluf(float x){ return 0.5f*x*(1.0f + erff(x*0.70710678118654752f)); }
__device__ __forceinline__ int bucketof(float x){
  int b = (int)floorf((x + 8.0f) * 256.0f);
  return min(max(b, 0), NB-1);
}

// bit-exact numpy distance key (r9-verified). Low 32 bits = original node idx.
__device__ __forceinline__ u64 make_key(float xi, float yi, float sqi,
                                        float cx, float cy, int jd, int self){
  float ax = cx*cx;  FPBAR(ax);
  float ay = cy*cy;  FPBAR(ay);
  float sqj = ax + ay;   FPBAR(sqj);
  float px = xi*cx;    FPBAR(px);
  float py = yi*cy;    FPBAR(py);
  float dt = px + py;    FPBAR(dt);            // NO-FMA dot
  float two_dt = 2.0f*dt;  FPBAR(two_dt);
  float ss = sqi + sqj;    FPBAR(ss);
  float d2 = ss - two_dt;  FPBAR(d2);
  float dist = __fsqrt_rn(fmaxf(d2, 0.0f));
  u64 key = ((u64)__float_as_uint(dist) << 32) | (unsigned)jd;
  return (jd == self) ? ~0ULL : key;
}

// branchless sorted top-16 insert (ascending u64 keys)
__device__ __forceinline__ void ladder_insert(u64* L, u64 key){
  bool c[KNN];
  #pragma unroll
  for (int t=0;t<KNN;t++) c[t] = key < L[t];
  #pragma unroll
  for (int t=KNN-1;t>=1;t--) L[t] = c[t-1] ? L[t-1] : (c[t] ? key : L[t]);
  L[0] = c[0] ? key : L[0];
}

// wave-level 64-list tournament merge; lane r gets r-th smallest of the union.
// LDS columns are lane-private -> no barrier needed (r12-verified).
__device__ __forceinline__ u64 wave_merge16(u64* slice, int lane, const u64* L)
{
  #pragma unroll
  for (int t=0;t<KNN;t++) slice[t*64 + lane] = L[t];
  int p = 0;
  u64 cur = slice[lane];
  u64 out16 = ~0ULL;
  for (int r=0;r<KNN;r++){
    u64 k = cur; int who = lane;
    #pragma unroll
    for (int o=32;o>0;o>>=1){
      u64 ok = __shfl_xor(k, o, 64);
      int ow = __shfl_xor(who, o, 64);
      if (ok < k){ k = ok; who = ow; }
    }
    if (lane == r) out16 = k;
    if (lane == who){
      ++p;
      cur = (p < KNN) ? slice[p*64 + lane] : ~0ULL;
    }
  }
  return out16;
}

// ---------------- dtype detection (proven: picks f32 here) ----------------
__global__ __launch_bounds__(256) void detect_kernel_r14(
    const unsigned* __restrict__ a, int na,
    const unsigned* __restrict__ b, int nb, int* __restrict__ flag)
{
  __shared__ int cnt;
  if (threadIdx.x == 0) cnt = 0;
  __syncthreads();
  int c = 0;
  for (int i = threadIdx.x; i < na; i += 256){
    int ex = (a[i] >> 7) & 0xFF;
    c += (ex >= 113 && ex <= 131) ? 1 : 0;
  }
  for (int i = threadIdx.x; i < nb; i += 256){
    int ex = (b[i] >> 7) & 0xFF;
    c += (ex >= 113 && ex <= 131) ? 1 : 0;
  }
  atomicAdd(&cnt, c);
  __syncthreads();
  if (threadIdx.x == 0) *flag = (cnt > (na + nb) / 2) ? 1 : 0;
}

// ---------------- decode all inputs to f32 workspace ----------------
struct SegTable {
  const void* src[16];
  float*      dst[16];
  int         cnt[16];
  int         total;
};

__global__ __launch_bounds__(256) void decode_kernel_r14(SegTable t, const int* __restrict__ flag)
{
  const int is_bf16 = *flag;
  for (int e = blockIdx.x*256 + threadIdx.x; e < t.total; e += gridDim.x*256){
    int rem = e, s = 0;
    while (rem >= t.cnt[s]){ rem -= t.cnt[s]; ++s; }
    float v;
    if (is_bf16) v = __uint_as_float(((unsigned)((const unsigned short*)t.src[s])[rem]) << 16);
    else         v = ((const float*)t.src[s])[rem];
    t.dst[s][rem] = v;
  }
}

// ---------------- bucket pre-pass ----------------
__global__ __launch_bounds__(256) void zero_kernel_r14(int* __restrict__ hist, int* __restrict__ cursor,
                                                       int* __restrict__ ocnt)
{
  int t = blockIdx.x*256 + threadIdx.x;
  if (t < NB){ hist[t] = 0; cursor[t] = 0; }
  if (blockIdx.x == 0 && threadIdx.x == 0) *ocnt = 0;
}

__global__ __launch_bounds__(256) void count_kernel_r14(const float* __restrict__ cents,
                                                        int* __restrict__ hist)
{
  int i = blockIdx.x*256 + threadIdx.x;
  if (i < NND) atomicAdd(&hist[bucketof(cents[2*i])], 1);
}

__global__ __launch_bounds__(1024) void scan_kernel_r14(const int* __restrict__ hist,
                                                        int* __restrict__ offs)
{
  __shared__ int s[1024];
  int t = threadIdx.x;
  int h0 = hist[t*4], h1 = hist[t*4+1], h2 = hist[t*4+2], h3 = hist[t*4+3];
  int tot = h0+h1+h2+h3;
  s[t] = tot;
  __syncthreads();
  for (int d=1; d<1024; d<<=1){
    int v = (t >= d) ? s[t-d] : 0;
    __syncthreads();
    s[t] += v;
    __syncthreads();
  }
  int excl = s[t] - tot;
  offs[t*4]   = excl;
  offs[t*4+1] = excl + h0;
  offs[t*4+2] = excl + h0 + h1;
  offs[t*4+3] = excl + h0 + h1 + h2;
}

__global__ __launch_bounds__(256) void scatter_kernel_r14(const float* __restrict__ cents,
    const int* __restrict__ offs, int* __restrict__ cursor,
    float2* __restrict__ sxy, int* __restrict__ sid)
{
  int i = blockIdx.x*256 + threadIdx.x;
  if (i < NND){
    float x = cents[2*i], y = cents[2*i+1];
    int b = bucketof(x);
    int pos = offs[b] + atomicAdd(&cursor[b], 1);
    sxy[pos] = make_float2(x, y);
    sid[pos] = i;
  }
}

// ---------------- kNN: ONE fixed 1024-window per node (wave-per-node), post-hoc check ----------------
// No adaptive loops, no per-round reductions: round positions depend only on r, so the
// 2 gathers/round pipeline freely. After one merge, bucket-edge geometry either proves
// the top-16 complete (vast majority) or defers the node to the brute-force kernel.
__global__ __launch_bounds__(256) void knn_fixed_r14(
    const float2* __restrict__ sxy, const int* __restrict__ sid,
    const float* __restrict__ cents, const int* __restrict__ offs,
    int* __restrict__ idx_out, float* __restrict__ w_out,
    int* __restrict__ ocnt, int* __restrict__ olist)
{
  __shared__ u64 lds_k[4][KNN*64];   // 32 KB
  const int lane = threadIdx.x & 63, wv = threadIdx.x >> 6;
  const int n = blockIdx.x*4 + wv;
  const float xi = cents[2*n];
  const float yi = cents[2*n+1];
  float sx = xi*xi; FPBAR(sx);
  float sy = yi*yi; FPBAR(sy);
  float sqi = sx + sy; FPBAR(sqi);

  const int start = offs[bucketof(xi)];
  const bool isR = lane < 32;
  const int lo = isR ? lane : (lane - 32);

  u64 L[KNN];
  #pragma unroll
  for (int t=0;t<KNN;t++) L[t] = ~0ULL;

  #pragma unroll 2
  for (int r=0;r<RW;r++){
    int myp = isR ? (start + r*32 + lo) : (start - 1 - r*32 - lo);
    bool act = (myp >= 0) && (myp < NND);
    float2 cu = make_float2(0.f, 0.f);
    int jd = -1;
    if (act){ cu = sxy[myp]; jd = sid[myp]; }
    u64 key = make_key(xi, yi, sqi, cu.x, cu.y, jd, n);
    if (!act) key = ~0ULL;
    ladder_insert(L, key);
  }

  // single merge -> exact top-16 of the 1024-window union
  u64 out16 = wave_merge16(&lds_k[wv][0], lane, L);
  float B = __uint_as_float((unsigned)(__shfl(out16, KNN-1, 64) >> 32));
  const float thr = B*B + 2e-4f;

  // completeness check via bucket-edge geometry (within-bucket order is arbitrary,
  // so bound unscanned x by the scanned edge's bucket edge)
  const int qr = min(start + RW*32, NND);   // scanned right: [start, qr)
  const int ql = max(start - RW*32, 0);     // scanned left:  [ql, start)
  bool ok;
  {
    bool rok = (qr >= NND);
    if (!rok){
      float xR = sxy[qr-1].x;
      float dxr = ((float)bucketof(xR)*BW - 8.0f) - xi;
      rok = (dxr > 0.0f) && (dxr*dxr > thr);
    }
    bool lok = (ql <= 0);
    if (!lok){
      float xL = sxy[ql].x;
      float dxl = xi - ((float)(bucketof(xL)+1)*BW - 8.0f);
      lok = (dxl > 0.0f) && (dxl*dxl > thr);
    }
    ok = rok && lok;
  }
  if (lane == 0 && !ok){
    int s = atomicAdd(ocnt, 1);
    olist[s] = n;
  }

  if (lane < KNN) idx_out[(size_t)n*KNN + lane] = (int)(unsigned)(out16 & 0xFFFFFFFFull);

  // weights: FPBAR pairwise tree (bit-exact since r9)
  u64 kt[KNN];
  #pragma unroll
  for (int t=0;t<KNN;t++) kt[t] = __shfl(out16, t, 64);
  float inv[KNN];
  #pragma unroll
  for (int t=0;t<KNN;t++){
    float d = __uint_as_float((unsigned)(kt[t] >> 32));
    inv[t] = __fdiv_rn(1.0f, fmaxf(d, 1e-4f));
  }
  float r8v[8];
  #pragma unroll
  for (int t=0;t<8;t++){ r8v[t] = inv[t] + inv[t+8]; FPBAR(r8v[t]); }
  float s01 = r8v[0]+r8v[1]; FPBAR(s01);
  float s23 = r8v[2]+r8v[3]; FPBAR(s23);
  float s45 = r8v[4]+r8v[5]; FPBAR(s45);
  float s67 = r8v[6]+r8v[7]; FPBAR(s67);
  float sA = s01+s23; FPBAR(sA);
  float sB = s45+s67; FPBAR(sB);
  float s = sA + sB;
  s = fmaxf(s, 1e-8f);
  if (lane < KNN){
    float d = __uint_as_float((unsigned)(out16 >> 32));
    float invL = __fdiv_rn(1.0f, fmaxf(d, 1e-4f));
    w_out[(size_t)n*KNN + lane] = __fdiv_rn(invL, s);
  }
}

// ---------------- brute-force fallback for deferred nodes (r13-verified, bit-exact) ----------------
__global__ __launch_bounds__(256) void knn_brute_r14(const float* __restrict__ cents,
    const int* __restrict__ olist, const int* __restrict__ ocnt,
    int* __restrict__ idx_out, float* __restrict__ w_out)
{
  __shared__ u64 s_k[KNN*256];
  __shared__ u64 bk[4]; __shared__ int bt[4];
  __shared__ u64 out_k[KNN];
  __shared__ int s_win;

  const int tid = threadIdx.x;
  const int cnt = *ocnt;
  for (int slot = blockIdx.x; slot < cnt; slot += gridDim.x){
    const int i = olist[slot];
    const float cx = cents[2*i];
    const float cy = cents[2*i+1];
    float sx = cx*cx;  FPBAR(sx);
    float sy = cy*cy;  FPBAR(sy);
    float sqi = sx + sy;  FPBAR(sqi);

    u64 L[KNN];
    #pragma unroll
    for (int t=0;t<KNN;t++) L[t] = ~0ULL;

    for (int j=tid; j<NND; j+=256){
      float2 cu = *(const float2*)(cents + 2*j);
      ladder_insert(L, make_key(cx, cy, sqi, cu.x, cu.y, j, i));
    }
    #pragma unroll
    for (int t=0;t<KNN;t++) s_k[t*256+tid] = L[t];
    __syncthreads();

    int p = 0;
    const int lane = tid & 63, wid = tid >> 6;
    for (int r=0;r<KNN;r++){
      u64 ck = s_k[p*256+tid]; int ct = tid;
      #pragma unroll
      for (int off=32; off>0; off>>=1){
        u64 ok = __shfl_down(ck, off, 64);
        int ot = __shfl_down(ct, off, 64);
        if (ok < ck){ ck = ok; ct = ot; }
      }
      if (lane == 0){ bk[wid]=ck; bt[wid]=ct; }
      __syncthreads();
      if (tid == 0){
        u64 mk=bk[0]; int mt=bt[0];
        for (int qq=1;qq<4;qq++) if (bk[qq] < mk){ mk=bk[qq]; mt=bt[qq]; }
        out_k[r]=mk; s_win=mt;
      }
      __syncthreads();
      if (tid == s_win) ++p;
      __syncthreads();
    }
    if (tid < KNN) idx_out[(size_t)i*KNN + tid] = (int)(unsigned)(out_k[tid] & 0xFFFFFFFFull);
    if (tid == 0){
      float inv[KNN];
      #pragma unroll
      for (int t=0;t<KNN;t++){
        float d = __uint_as_float((unsigned)(out_k[t] >> 32));
        inv[t] = __fdiv_rn(1.0f, fmaxf(d, 1e-4f));
      }
      float r8v[8];
      #pragma unroll
      for (int t=0;t<8;t++){ r8v[t] = inv[t] + inv[t+8]; FPBAR(r8v[t]); }
      float s01 = r8v[0]+r8v[1]; FPBAR(s01);
      float s23 = r8v[2]+r8v[3]; FPBAR(s23);
      float s45 = r8v[4]+r8v[5]; FPBAR(s45);
      float s67 = r8v[6]+r8v[7]; FPBAR(s67);
      float sA = s01+s23; FPBAR(sA);
      float sB = s45+s67; FPBAR(sB);
      float s = sA + sB;
      s = fmaxf(s, 1e-8f);
      #pragma unroll
      for (int t=0;t<KNN;t++) w_out[(size_t)i*KNN + t] = __fdiv_rn(inv[t], s);
    }
    __syncthreads();
  }
}

// ---------------- GEMM: C[M,OUT] = gelu(A1@W1^T (+ A2@W2^T) (+ bias)) ----------------
template<int OUT, bool DUAL, bool BIAS>
__global__ __launch_bounds__(256) void mm_kernel_r14(
    const float* __restrict__ A1, const float* __restrict__ A2,
    const float* __restrict__ W1, const float* __restrict__ W2,
    const float* __restrict__ bias, float* __restrict__ C)
{
  constexpr int KC = 16;
  constexpr int TM = 32;
  constexpr int WS = KC + 4;
  constexpr int NQ = OUT / 64;
  __shared__ float Wl1[OUT*WS];
  __shared__ float Wl2[DUAL ? OUT*WS : 1];
  __shared__ float Al1[TM*KC];
  __shared__ float Al2[DUAL ? TM*KC : 1];

  const int tid = threadIdx.x;
  const int cg  = tid & 63;
  const int rg  = tid >> 6;
  const int m0  = blockIdx.x * TM;

  float acc[8][NQ];
  #pragma unroll
  for (int r=0;r<8;r++)
    #pragma unroll
    for (int q=0;q<NQ;q++) acc[r][q] = 0.f;

  for (int c0=0; c0<DM; c0+=KC){
    for (int e=tid; e < OUT*(KC/4); e += 256){
      int row = e >> 2;
      int c4  = (e & 3)*4;
      *(float4*)&Wl1[row*WS + c4] = *(const float4*)(W1 + (size_t)row*DM + c0 + c4);
      if (DUAL)
        *(float4*)&Wl2[row*WS + c4] = *(const float4*)(W2 + (size_t)row*DM + c0 + c4);
    }
    for (int e=tid; e < TM*(KC/4); e += 256){
      int row = e >> 2;
      int c4  = (e & 3)*4;
      size_t gi = (size_t)(m0+row)*DM + c0 + c4;
      *(float4*)&Al1[row*KC+c4] = *(const float4*)(A1 + gi);
      if (DUAL) *(float4*)&Al2[row*KC+c4] = *(const float4*)(A2 + gi);
    }
    __syncthreads();
    #pragma unroll
    for (int k4=0; k4<KC/4; k4++){
      float4 wv1[NQ]; float4 wv2[NQ];
      #pragma unroll
      for (int q=0;q<NQ;q++){
        wv1[q] = *(const float4*)&Wl1[(cg+64*q)*WS + k4*4];
        if (DUAL) wv2[q] = *(const float4*)&Wl2[(cg+64*q)*WS + k4*4];
      }
      #pragma unroll
      for (int r=0;r<8;r++){
        float4 a1 = *(const float4*)&Al1[(rg*8+r)*KC + k4*4];
        float4 a2;
        if (DUAL) a2 = *(const float4*)&Al2[(rg*8+r)*KC + k4*4];
        #pragma unroll
        for (int q=0;q<NQ;q++){
          float s = acc[r][q];
          s = fmaf(a1.x, wv1[q].x, s);
          s = fmaf(a1.y, wv1[q].y, s);
          s = fmaf(a1.z, wv1[q].z, s);
          s = fmaf(a1.w, wv1[q].w, s);
          if (DUAL){
            s = fmaf(a2.x, wv2[q].x, s);
            s = fmaf(a2.y, wv2[q].y, s);
            s = fmaf(a2.z, wv2[q].z, s);
            s = fmaf(a2.w, wv2[q].w, s);
          }
          acc[r][q] = s;
        }
      }
    }
    __syncthreads();
  }
  #pragma unroll
  for (int q=0;q<NQ;q++){
    int d = cg + 64*q;
    float bv = BIAS ? bias[d] : 0.f;
    #pragma unroll
    for (int r=0;r<8;r++){
      float v = geluf(acc[r][q] + bv);
      C[(size_t)(m0 + rg*8 + r)*OUT + d] = v;
    }
  }
}

// ---------------- weighted neighbor aggregation ----------------
__global__ __launch_bounds__(256) void agg_kernel_r14(const float* __restrict__ h,
    const int* __restrict__ idx, const float* __restrict__ w, float* __restrict__ agg)
{
  const int lane = threadIdx.x & 63, wid = threadIdx.x >> 6;
  const int n = blockIdx.x*4 + wid;
  const int base = n*KNN;
  float4 acc = make_float4(0.f,0.f,0.f,0.f);
  for (int k=0;k<KNN;k++){
    int j = idx[base+k];
    float wk = w[base+k];
    float4 hv = *(const float4*)(h + (size_t)j*DM + lane*4);
    acc.x = fmaf(wk, hv.x, acc.x);
    acc.y = fmaf(wk, hv.y, acc.y);
    acc.z = fmaf(wk, hv.z, acc.z);
    acc.w = fmaf(wk, hv.w, acc.w);
  }
  *(float4*)(agg + (size_t)n*DM + lane*4) = acc;
}

// ---------------- h = h + layernorm(tmp)*g + b ----------------
__global__ __launch_bounds__(256) void ln_res_kernel_r14(float* __restrict__ h,
    const float* __restrict__ tmp, const float* __restrict__ g, const float* __restrict__ b)
{
  const int lane = threadIdx.x & 63, wid = threadIdx.x >> 6;
  const int n = blockIdx.x*4 + wid;
  float4 x = *(const float4*)(tmp + (size_t)n*DM + lane*4);
  float s = (x.x + x.y) + (x.z + x.w);
  #pragma unroll
  for (int off=32; off>0; off>>=1) s += __shfl_xor(s, off, 64);
  float mu = s * (1.0f/DM);
  float dx0 = x.x-mu, dx1 = x.y-mu, dx2 = x.z-mu, dx3 = x.w-mu;
  float v = (dx0*dx0 + dx1*dx1) + (dx2*dx2 + dx3*dx3);
  #pragma unroll
  for (int off=32; off>0; off>>=1) v += __shfl_xor(v, off, 64);
  float rs = 1.0f / sqrtf(v * (1.0f/DM) + 1e-5f);
  int c = lane*4;
  float4 gv = *(const float4*)(g + c);
  float4 bv = *(const float4*)(b + c);
  float4 hv = *(const float4*)(h + (size_t)n*DM + c);
  hv.x += dx0*rs*gv.x + bv.x;
  hv.y += dx1*rs*gv.y + bv.y;
  hv.z += dx2*rs*gv.z + bv.z;
  hv.w += dx3*rs*gv.w + bv.w;
  *(float4*)(h + (size_t)n*DM + c) = hv;
}

// ---------------- final: out[n] = sigmoid(dot(hid[n], w2) + b2), dtype per flag ----------------
__global__ __launch_bounds__(256) void cls2_kernel_r14(const float* __restrict__ hid,
    const float* __restrict__ w2, const float* __restrict__ b2,
    void* __restrict__ out, const int* __restrict__ flag)
{
  const int lane = threadIdx.x & 63, wid = threadIdx.x >> 6;
  const int n = blockIdx.x*4 + wid;
  float a = hid[(size_t)n*128 + lane]      * w2[lane]
          + hid[(size_t)n*128 + 64 + lane] * w2[64+lane];
  #pragma unroll
  for (int off=32; off>0; off>>=1) a += __shfl_xor(a, off, 64);
  if (lane == 0){
    float v = 1.0f / (1.0f + expf(-(a + b2[0])));
    if (*flag) ((__hip_bfloat16*)out)[n] = __float2bfloat16(v);
    else       ((float*)out)[n] = v;
  }
}

extern "C" void kernel_launch(void* const* d_in, const int* in_sizes, int n_in,
                              void* d_out, int out_size, void* d_ws, size_t ws_size,
                              hipStream_t stream)
{
  // ---- workspace layout (~44.9 MB), fully rewritten every call ----
  char* base = (char*)d_ws;
  int*   flag = (int*)base;                                   // 16 B slot
  float* wreg = (float*)(base + 16);
  static const int sizes[16] = {
    NND*256, NND*2, 256*256, 256, 256*256, 256*256, 256, 256,
    256*256, 256*256, 256, 256, 128*256, 128, 128, 1
  };
  float* ptrs[16];
  {
    float* p = wreg;
    for (int i = 2; i < 16; i++){ ptrs[i] = p; p += sizes[i]; }
    ptrs[1] = p;                          // cents  [24,000]
    p += NND*2;
    ptrs[0] = p;                          // feats  [3,072,000]  (reused as tmp later)
  }
  float* F    = ptrs[0];
  float* C    = ptrs[1];
  float* h    = F + (size_t)NND*DM;
  float* agg  = h + (size_t)NND*DM;
  float* hid  = agg + (size_t)NND*DM;
  int*  gidx  = (int*)(hid + (size_t)NND*128);
  float* gw   = (float*)(gidx + (size_t)NND*KNN);
  // knn pre-pass scratch
  float2* sxy   = (float2*)(gw + (size_t)NND*KNN);
  int*    sid   = (int*)(sxy + NND);
  int*    hist  = sid + NND;
  int*    cursor= hist + NB;
  int*    offs  = cursor + NB;
  int*    ocnt  = offs + NB;
  int*    olist = ocnt + 1;               // up to 12000 ints

  // ---- dtype detect + decode ----
  detect_kernel_r14<<<1, 256, 0, stream>>>((const unsigned*)d_in[1], 4096,
                                           (const unsigned*)d_in[0], 16384, flag);
  SegTable t;
  int total = 0;
  for (int i = 0; i < 16; i++){
    t.src[i] = d_in[i];
    t.dst[i] = ptrs[i];
    t.cnt[i] = sizes[i];
    total += sizes[i];
  }
  t.total = total;
  decode_kernel_r14<<<(total + 255)/256, 256, 0, stream>>>(t, flag);

  const float* enc_w  = ptrs[2];  const float* enc_b  = ptrs[3];
  const float* g1_ws  = ptrs[4];  const float* g1_wn  = ptrs[5];
  const float* g1_g   = ptrs[6];  const float* g1_b   = ptrs[7];
  const float* g2_ws  = ptrs[8];  const float* g2_wn  = ptrs[9];
  const float* g2_g   = ptrs[10]; const float* g2_b   = ptrs[11];
  const float* cls_w1 = ptrs[12]; const float* cls_b1 = ptrs[13];
  const float* cls_w2 = ptrs[14]; const float* cls_b2 = ptrs[15];

  dim3 b256(256);
  // knn pre-pass: bucket counting sort by x (+ zero outlier counter)
  zero_kernel_r14<<<(NB + 255)/256, b256, 0, stream>>>(hist, cursor, ocnt);
  count_kernel_r14<<<(NND + 255)/256, b256, 0, stream>>>(C, hist);
  scan_kernel_r14<<<1, 1024, 0, stream>>>(hist, offs);
  scatter_kernel_r14<<<(NND + 255)/256, b256, 0, stream>>>(C, offs, cursor, sxy, sid);
  // encoder: h = gelu(feats @ enc_w^T + enc_b)
  mm_kernel_r14<256,false,true><<<NND/32, b256, 0, stream>>>(F, nullptr, enc_w, nullptr, enc_b, h);
  // knn: fixed-window wave-per-node + brute fallback for deferred nodes
  knn_fixed_r14<<<NND/4, b256, 0, stream>>>(sxy, sid, C, offs, gidx, gw, ocnt, olist);
  knn_brute_r14<<<256, b256, 0, stream>>>(C, olist, ocnt, gidx, gw);
  // sage layer 1 (tmp := F, feats dead after encoder)
  agg_kernel_r14<<<NND/4, b256, 0, stream>>>(h, gidx, gw, agg);
  mm_kernel_r14<256,true,false><<<NND/32, b256, 0, stream>>>(h, agg, g1_ws, g1_wn, nullptr, F);
  ln_res_kernel_r14<<<NND/4, b256, 0, stream>>>(h, F, g1_g, g1_b);
  // sage layer 2
  agg_kernel_r14<<<NND/4, b256, 0, stream>>>(h, gidx, gw, agg);
  mm_kernel_r14<256,true,false><<<NND/32, b256, 0, stream>>>(h, agg, g2_ws, g2_wn, nullptr, F);
  ln_res_kernel_r14<<<NND/4, b256, 0, stream>>>(h, F, g2_g, g2_b);
  // classifier
  mm_kernel_r14<128,false,true><<<NND/32, b256, 0, stream>>>(h, nullptr, cls_w1, nullptr, cls_b1, hid);
  cls2_kernel_r14<<<NND/4, b256, 0, stream>>>(hid, cls_w2, cls_b2, d_out, flag);
}

// Round 15
// 569.175 us; speedup vs baseline: 1.5850x; 1.1237x over previous
//
#include <hip/hip_runtime.h>
#include <hip/hip_bf16.h>
#include <stdint.h>

#define NND 12000
#define DM  256
#define KNN 16
#define NB  4096          // x-buckets
#define BW  0.00390625f   // bucket width = 1/256 over [-8, 8)
#define RW  16            // fixed-window rounds (16*64 = 1024 candidates)

// Opaque register barrier: prevents FMA contraction (r9: made knn bit-match numpy
// -> absmax 0.0. DO NOT REMOVE).
#define FPBAR(x) asm volatile("" : "+v"(x))

typedef unsigned long long u64;

__device__ __forceinline__ float geluf(float x){ return 0.5f*x*(1.0f + erff(x*0.70710678118654752f)); }
__device__ __forceinline__ int bucketof(float x){
  int b = (int)floorf((x + 8.0f) * 256.0f);
  return min(max(b, 0), NB-1);
}

// bit-exact numpy distance key (r9-verified). Low 32 bits = original node idx.
__device__ __forceinline__ u64 make_key(float xi, float yi, float sqi,
                                        float cx, float cy, int jd, int self){
  float ax = cx*cx;  FPBAR(ax);
  float ay = cy*cy;  FPBAR(ay);
  float sqj = ax + ay;   FPBAR(sqj);
  float px = xi*cx;    FPBAR(px);
  float py = yi*cy;    FPBAR(py);
  float dt = px + py;    FPBAR(dt);            // NO-FMA dot
  float two_dt = 2.0f*dt;  FPBAR(two_dt);
  float ss = sqi + sqj;    FPBAR(ss);
  float d2 = ss - two_dt;  FPBAR(d2);
  float dist = __fsqrt_rn(fmaxf(d2, 0.0f));
  u64 key = ((u64)__float_as_uint(dist) << 32) | (unsigned)jd;
  return (jd == self) ? ~0ULL : key;
}

// branchless sorted top-16 insert (ascending u64 keys)
__device__ __forceinline__ void ladder_insert(u64* L, u64 key){
  bool c[KNN];
  #pragma unroll
  for (int t=0;t<KNN;t++) c[t] = key < L[t];
  #pragma unroll
  for (int t=KNN-1;t>=1;t--) L[t] = c[t-1] ? L[t-1] : (c[t] ? key : L[t]);
  L[0] = c[0] ? key : L[0];
}

// wave-level 64-list tournament merge; lane r gets r-th smallest of the union.
// LDS columns are lane-private -> no barrier needed (r12-verified).
__device__ __forceinline__ u64 wave_merge16(u64* slice, int lane, const u64* L)
{
  #pragma unroll
  for (int t=0;t<KNN;t++) slice[t*64 + lane] = L[t];
  int p = 0;
  u64 cur = slice[lane];
  u64 out16 = ~0ULL;
  for (int r=0;r<KNN;r++){
    u64 k = cur; int who = lane;
    #pragma unroll
    for (int o=32;o>0;o>>=1){
      u64 ok = __shfl_xor(k, o, 64);
      int ow = __shfl_xor(who, o, 64);
      if (ok < k){ k = ok; who = ow; }
    }
    if (lane == r) out16 = k;
    if (lane == who){
      ++p;
      cur = (p < KNN) ? slice[p*64 + lane] : ~0ULL;
    }
  }
  return out16;
}

// shared epilogue: weights via numpy pairwise tree (bit-exact since r9)
__device__ __forceinline__ void write_outputs(u64 out16, int lane, int n,
    int* __restrict__ idx_out, float* __restrict__ w_out)
{
  if (lane < KNN) idx_out[(size_t)n*KNN + lane] = (int)(unsigned)(out16 & 0xFFFFFFFFull);
  u64 kt[KNN];
  #pragma unroll
  for (int t=0;t<KNN;t++) kt[t] = __shfl(out16, t, 64);
  float inv[KNN];
  #pragma unroll
  for (int t=0;t<KNN;t++){
    float d = __uint_as_float((unsigned)(kt[t] >> 32));
    inv[t] = __fdiv_rn(1.0f, fmaxf(d, 1e-4f));
  }
  float r8v[8];
  #pragma unroll
  for (int t=0;t<8;t++){ r8v[t] = inv[t] + inv[t+8]; FPBAR(r8v[t]); }
  float s01 = r8v[0]+r8v[1]; FPBAR(s01);
  float s23 = r8v[2]+r8v[3]; FPBAR(s23);
  float s45 = r8v[4]+r8v[5]; FPBAR(s45);
  float s67 = r8v[6]+r8v[7]; FPBAR(s67);
  float sA = s01+s23; FPBAR(sA);
  float sB = s45+s67; FPBAR(sB);
  float s = sA + sB;
  s = fmaxf(s, 1e-8f);
  if (lane < KNN){
    float d = __uint_as_float((unsigned)(out16 >> 32));
    float invL = __fdiv_rn(1.0f, fmaxf(d, 1e-4f));
    w_out[(size_t)n*KNN + lane] = __fdiv_rn(invL, s);
  }
}

// ---------------- dtype detection (proven: picks f32 here) ----------------
__global__ __launch_bounds__(256) void detect_kernel_r15(
    const unsigned* __restrict__ a, int na,
    const unsigned* __restrict__ b, int nb, int* __restrict__ flag)
{
  __shared__ int cnt;
  if (threadIdx.x == 0) cnt = 0;
  __syncthreads();
  int c = 0;
  for (int i = threadIdx.x; i < na; i += 256){
    int ex = (a[i] >> 7) & 0xFF;
    c += (ex >= 113 && ex <= 131) ? 1 : 0;
  }
  for (int i = threadIdx.x; i < nb; i += 256){
    int ex = (b[i] >> 7) & 0xFF;
    c += (ex >= 113 && ex <= 131) ? 1 : 0;
  }
  atomicAdd(&cnt, c);
  __syncthreads();
  if (threadIdx.x == 0) *flag = (cnt > (na + nb) / 2) ? 1 : 0;
}

// ---------------- decode all inputs to f32 workspace ----------------
struct SegTable {
  const void* src[16];
  float*      dst[16];
  int         cnt[16];
  int         total;
};

__global__ __launch_bounds__(256) void decode_kernel_r15(SegTable t, const int* __restrict__ flag)
{
  const int is_bf16 = *flag;
  for (int e = blockIdx.x*256 + threadIdx.x; e < t.total; e += gridDim.x*256){
    int rem = e, s = 0;
    while (rem >= t.cnt[s]){ rem -= t.cnt[s]; ++s; }
    float v;
    if (is_bf16) v = __uint_as_float(((unsigned)((const unsigned short*)t.src[s])[rem]) << 16);
    else         v = ((const float*)t.src[s])[rem];
    t.dst[s][rem] = v;
  }
}

// ---------------- bucket pre-pass ----------------
__global__ __launch_bounds__(256) void zero_kernel_r15(int* __restrict__ hist, int* __restrict__ cursor,
                                                       int* __restrict__ ocnt)
{
  int t = blockIdx.x*256 + threadIdx.x;
  if (t < NB){ hist[t] = 0; cursor[t] = 0; }
  if (blockIdx.x == 0 && threadIdx.x == 0) *ocnt = 0;
}

__global__ __launch_bounds__(256) void count_kernel_r15(const float* __restrict__ cents,
                                                        int* __restrict__ hist)
{
  int i = blockIdx.x*256 + threadIdx.x;
  if (i < NND) atomicAdd(&hist[bucketof(cents[2*i])], 1);
}

__global__ __launch_bounds__(1024) void scan_kernel_r15(const int* __restrict__ hist,
                                                        int* __restrict__ offs)
{
  __shared__ int s[1024];
  int t = threadIdx.x;
  int h0 = hist[t*4], h1 = hist[t*4+1], h2 = hist[t*4+2], h3 = hist[t*4+3];
  int tot = h0+h1+h2+h3;
  s[t] = tot;
  __syncthreads();
  for (int d=1; d<1024; d<<=1){
    int v = (t >= d) ? s[t-d] : 0;
    __syncthreads();
    s[t] += v;
    __syncthreads();
  }
  int excl = s[t] - tot;
  offs[t*4]   = excl;
  offs[t*4+1] = excl + h0;
  offs[t*4+2] = excl + h0 + h1;
  offs[t*4+3] = excl + h0 + h1 + h2;
}

__global__ __launch_bounds__(256) void scatter_kernel_r15(const float* __restrict__ cents,
    const int* __restrict__ offs, int* __restrict__ cursor,
    float2* __restrict__ sxy, int* __restrict__ sid)
{
  int i = blockIdx.x*256 + threadIdx.x;
  if (i < NND){
    float x = cents[2*i], y = cents[2*i+1];
    int b = bucketof(x);
    int pos = offs[b] + atomicAdd(&cursor[b], 1);
    sxy[pos] = make_float2(x, y);
    sid[pos] = i;
  }
}

// ---------------- kNN: ONE fixed 1024-window per node (wave-per-node), post-hoc check ----------------
__global__ __launch_bounds__(256) void knn_fixed_r15(
    const float2* __restrict__ sxy, const int* __restrict__ sid,
    const float* __restrict__ cents, const int* __restrict__ offs,
    int* __restrict__ idx_out, float* __restrict__ w_out,
    int* __restrict__ ocnt, int* __restrict__ olist, float* __restrict__ othr)
{
  __shared__ u64 lds_k[4][KNN*64];   // 32 KB
  const int lane = threadIdx.x & 63, wv = threadIdx.x >> 6;
  const int n = blockIdx.x*4 + wv;
  const float xi = cents[2*n];
  const float yi = cents[2*n+1];
  float sx = xi*xi; FPBAR(sx);
  float sy = yi*yi; FPBAR(sy);
  float sqi = sx + sy; FPBAR(sqi);

  const int start = offs[bucketof(xi)];
  const bool isR = lane < 32;
  const int lo = isR ? lane : (lane - 32);

  u64 L[KNN];
  #pragma unroll
  for (int t=0;t<KNN;t++) L[t] = ~0ULL;

  #pragma unroll 2
  for (int r=0;r<RW;r++){
    int myp = isR ? (start + r*32 + lo) : (start - 1 - r*32 - lo);
    bool act = (myp >= 0) && (myp < NND);
    float2 cu = make_float2(0.f, 0.f);
    int jd = -1;
    if (act){ cu = sxy[myp]; jd = sid[myp]; }
    u64 key = make_key(xi, yi, sqi, cu.x, cu.y, jd, n);
    if (!act) key = ~0ULL;
    ladder_insert(L, key);
  }

  // single merge -> exact top-16 of the 1024-window union
  u64 out16 = wave_merge16(&lds_k[wv][0], lane, L);
  float B = __uint_as_float((unsigned)(__shfl(out16, KNN-1, 64) >> 32));
  const float thr = B*B + 2e-4f;

  // completeness check via bucket-edge geometry
  const int qr = min(start + RW*32, NND);   // scanned right: [start, qr)
  const int ql = max(start - RW*32, 0);     // scanned left:  [ql, start)
  bool ok;
  {
    bool rok = (qr >= NND);
    if (!rok){
      float xR = sxy[qr-1].x;
      float dxr = ((float)bucketof(xR)*BW - 8.0f) - xi;
      rok = (dxr > 0.0f) && (dxr*dxr > thr);
    }
    bool lok = (ql <= 0);
    if (!lok){
      float xL = sxy[ql].x;
      float dxl = xi - ((float)(bucketof(xL)+1)*BW - 8.0f);
      lok = (dxl > 0.0f) && (dxl*dxl > thr);
    }
    ok = rok && lok;
  }
  if (lane == 0 && !ok){
    int s = atomicAdd(ocnt, 1);
    olist[s] = n;
    othr[s] = thr;
  }

  write_outputs(out16, lane, n, idx_out, w_out);
}

// ---------------- bounded rescan for deferred nodes (wave-per-node, exact) ----------------
// B from the 1024-window bounds the final 16th from above; every true top-16 member
// has |dx| <= dist <= B <= rB=sqrt(thr). Rescanning all positions in buckets
// overlapping [xi-rB, xi+rB] (bucket-aligned superset) gives the exact top-16.
// Margin: rB-B ~ 1e-4/B vs dist-rounding skew <= 7.5e-6/B -> 13x guard.
__global__ __launch_bounds__(256) void knn_ext_r15(
    const float2* __restrict__ sxy, const int* __restrict__ sid,
    const float* __restrict__ cents, const int* __restrict__ offs,
    const int* __restrict__ olist, const float* __restrict__ othr,
    const int* __restrict__ ocnt,
    int* __restrict__ idx_out, float* __restrict__ w_out)
{
  __shared__ u64 lds_k[4][KNN*64];   // 32 KB
  const int lane = threadIdx.x & 63, wv = threadIdx.x >> 6;
  const int cnt = *ocnt;

  for (int slot = blockIdx.x*4 + wv; slot < cnt; slot += gridDim.x*4){
    const int n = olist[slot];
    const float thr = othr[slot];
    const float rB = __fsqrt_rn(thr) * (1.0f + 2e-6f);  // ulp guard on sqrt
    const float xi = cents[2*n];
    const float yi = cents[2*n+1];
    float sx = xi*xi; FPBAR(sx);
    float sy = yi*yi; FPBAR(sy);
    float sqi = sx + sy; FPBAR(sqi);

    const int bL = bucketof(xi - rB);
    const int bR = bucketof(xi + rB);
    const int posL = offs[bL];
    const int posR = (bR + 1 < NB) ? offs[bR + 1] : NND;

    u64 L[KNN];
    #pragma unroll
    for (int t=0;t<KNN;t++) L[t] = ~0ULL;

    for (int p = posL + lane; p < posR; p += 64){
      float2 cu = sxy[p];
      ladder_insert(L, make_key(xi, yi, sqi, cu.x, cu.y, sid[p], n));
    }

    u64 out16 = wave_merge16(&lds_k[wv][0], lane, L);
    write_outputs(out16, lane, n, idx_out, w_out);
  }
}

// ---------------- GEMM: C[M,OUT] = gelu(A1@W1^T (+ A2@W2^T) (+ bias)) ----------------
template<int OUT, bool DUAL, bool BIAS>
__global__ __launch_bounds__(256) void mm_kernel_r15(
    const float* __restrict__ A1, const float* __restrict__ A2,
    const float* __restrict__ W1, const float* __restrict__ W2,
    const float* __restrict__ bias, float* __restrict__ C)
{
  constexpr int KC = 16;
  constexpr int TM = 32;
  constexpr int WS = KC + 4;
  constexpr int NQ = OUT / 64;
  __shared__ float Wl1[OUT*WS];
  __shared__ float Wl2[DUAL ? OUT*WS : 1];
  __shared__ float Al1[TM*KC];
  __shared__ float Al2[DUAL ? TM*KC : 1];

  const int tid = threadIdx.x;
  const int cg  = tid & 63;
  const int rg  = tid >> 6;
  const int m0  = blockIdx.x * TM;

  float acc[8][NQ];
  #pragma unroll
  for (int r=0;r<8;r++)
    #pragma unroll
    for (int q=0;q<NQ;q++) acc[r][q] = 0.f;

  for (int c0=0; c0<DM; c0+=KC){
    for (int e=tid; e < OUT*(KC/4); e += 256){
      int row = e >> 2;
      int c4  = (e & 3)*4;
      *(float4*)&Wl1[row*WS + c4] = *(const float4*)(W1 + (size_t)row*DM + c0 + c4);
      if (DUAL)
        *(float4*)&Wl2[row*WS + c4] = *(const float4*)(W2 + (size_t)row*DM + c0 + c4);
    }
    for (int e=tid; e < TM*(KC/4); e += 256){
      int row = e >> 2;
      int c4  = (e & 3)*4;
      size_t gi = (size_t)(m0+row)*DM + c0 + c4;
      *(float4*)&Al1[row*KC+c4] = *(const float4*)(A1 + gi);
      if (DUAL) *(float4*)&Al2[row*KC+c4] = *(const float4*)(A2 + gi);
    }
    __syncthreads();
    #pragma unroll
    for (int k4=0; k4<KC/4; k4++){
      float4 wv1[NQ]; float4 wv2[NQ];
      #pragma unroll
      for (int q=0;q<NQ;q++){
        wv1[q] = *(const float4*)&Wl1[(cg+64*q)*WS + k4*4];
        if (DUAL) wv2[q] = *(const float4*)&Wl2[(cg+64*q)*WS + k4*4];
      }
      #pragma unroll
      for (int r=0;r<8;r++){
        float4 a1 = *(const float4*)&Al1[(rg*8+r)*KC + k4*4];
        float4 a2;
        if (DUAL) a2 = *(const float4*)&Al2[(rg*8+r)*KC + k4*4];
        #pragma unroll
        for (int q=0;q<NQ;q++){
          float s = acc[r][q];
          s = fmaf(a1.x, wv1[q].x, s);
          s = fmaf(a1.y, wv1[q].y, s);
          s = fmaf(a1.z, wv1[q].z, s);
          s = fmaf(a1.w, wv1[q].w, s);
          if (DUAL){
            s = fmaf(a2.x, wv2[q].x, s);
            s = fmaf(a2.y, wv2[q].y, s);
            s = fmaf(a2.z, wv2[q].z, s);
            s = fmaf(a2.w, wv2[q].w, s);
          }
          acc[r][q] = s;
        }
      }
    }
    __syncthreads();
  }
  #pragma unroll
  for (int q=0;q<NQ;q++){
    int d = cg + 64*q;
    float bv = BIAS ? bias[d] : 0.f;
    #pragma unroll
    for (int r=0;r<8;r++){
      float v = geluf(acc[r][q] + bv);
      C[(size_t)(m0 + rg*8 + r)*OUT + d] = v;
    }
  }
}

// ---------------- weighted neighbor aggregation ----------------
__global__ __launch_bounds__(256) void agg_kernel_r15(const float* __restrict__ h,
    const int* __restrict__ idx, const float* __restrict__ w, float* __restrict__ agg)
{
  const int lane = threadIdx.x & 63, wid = threadIdx.x >> 6;
  const int n = blockIdx.x*4 + wid;
  const int base = n*KNN;
  float4 acc = make_float4(0.f,0.f,0.f,0.f);
  for (int k=0;k<KNN;k++){
    int j = idx[base+k];
    float wk = w[base+k];
    float4 hv = *(const float4*)(h + (size_t)j*DM + lane*4);
    acc.x = fmaf(wk, hv.x, acc.x);
    acc.y = fmaf(wk, hv.y, acc.y);
    acc.z = fmaf(wk, hv.z, acc.z);
    acc.w = fmaf(wk, hv.w, acc.w);
  }
  *(float4*)(agg + (size_t)n*DM + lane*4) = acc;
}

// ---------------- h = h + layernorm(tmp)*g + b ----------------
__global__ __launch_bounds__(256) void ln_res_kernel_r15(float* __restrict__ h,
    const float* __restrict__ tmp, const float* __restrict__ g, const float* __restrict__ b)
{
  const int lane = threadIdx.x & 63, wid = threadIdx.x >> 6;
  const int n = blockIdx.x*4 + wid;
  float4 x = *(const float4*)(tmp + (size_t)n*DM + lane*4);
  float s = (x.x + x.y) + (x.z + x.w);
  #pragma unroll
  for (int off=32; off>0; off>>=1) s += __shfl_xor(s, off, 64);
  float mu = s * (1.0f/DM);
  float dx0 = x.x-mu, dx1 = x.y-mu, dx2 = x.z-mu, dx3 = x.w-mu;
  float v = (dx0*dx0 + dx1*dx1) + (dx2*dx2 + dx3*dx3);
  #pragma unroll
  for (int off=32; off>0; off>>=1) v += __shfl_xor(v, off, 64);
  float rs = 1.0f / sqrtf(v * (1.0f/DM) + 1e-5f);
  int c = lane*4;
  float4 gv = *(const float4*)(g + c);
  float4 bv = *(const float4*)(b + c);
  float4 hv = *(const float4*)(h + (size_t)n*DM + c);
  hv.x += dx0*rs*gv.x + bv.x;
  hv.y += dx1*rs*gv.y + bv.y;
  hv.z += dx2*rs*gv.z + bv.z;
  hv.w += dx3*rs*gv.w + bv.w;
  *(float4*)(h + (size_t)n*DM + c) = hv;
}

// ---------------- final: out[n] = sigmoid(dot(hid[n], w2) + b2), dtype per flag ----------------
__global__ __launch_bounds__(256) void cls2_kernel_r15(const float* __restrict__ hid,
    const float* __restrict__ w2, const float* __restrict__ b2,
    void* __restrict__ out, const int* __restrict__ flag)
{
  const int lane = threadIdx.x & 63, wid = threadIdx.x >> 6;
  const int n = blockIdx.x*4 + wid;
  float a = hid[(size_t)n*128 + lane]      * w2[lane]
          + hid[(size_t)n*128 + 64 + lane] * w2[64+lane];
  #pragma unroll
  for (int off=32; off>0; off>>=1) a += __shfl_xor(a, off, 64);
  if (lane == 0){
    float v = 1.0f / (1.0f + expf(-(a + b2[0])));
    if (*flag) ((__hip_bfloat16*)out)[n] = __float2bfloat16(v);
    else       ((float*)out)[n] = v;
  }
}

extern "C" void kernel_launch(void* const* d_in, const int* in_sizes, int n_in,
                              void* d_out, int out_size, void* d_ws, size_t ws_size,
                              hipStream_t stream)
{
  // ---- workspace layout (~45 MB), fully rewritten every call ----
  char* base = (char*)d_ws;
  int*   flag = (int*)base;                                   // 16 B slot
  float* wreg = (float*)(base + 16);
  static const int sizes[16] = {
    NND*256, NND*2, 256*256, 256, 256*256, 256*256, 256, 256,
    256*256, 256*256, 256, 256, 128*256, 128, 128, 1
  };
  float* ptrs[16];
  {
    float* p = wreg;
    for (int i = 2; i < 16; i++){ ptrs[i] = p; p += sizes[i]; }
    ptrs[1] = p;                          // cents  [24,000]
    p += NND*2;
    ptrs[0] = p;                          // feats  [3,072,000]  (reused as tmp later)
  }
  float* F    = ptrs[0];
  float* C    = ptrs[1];
  float* h    = F + (size_t)NND*DM;
  float* agg  = h + (size_t)NND*DM;
  float* hid  = agg + (size_t)NND*DM;
  int*  gidx  = (int*)(hid + (size_t)NND*128);
  float* gw   = (float*)(gidx + (size_t)NND*KNN);
  // knn pre-pass scratch
  float2* sxy   = (float2*)(gw + (size_t)NND*KNN);
  int*    sid   = (int*)(sxy + NND);
  int*    hist  = sid + NND;
  int*    cursor= hist + NB;
  int*    offs  = cursor + NB;
  int*    ocnt  = offs + NB;
  int*    olist = ocnt + 1;               // up to 12000 ints
  float*  othr  = (float*)(olist + NND);  // thr per deferred node

  // ---- dtype detect + decode ----
  detect_kernel_r15<<<1, 256, 0, stream>>>((const unsigned*)d_in[1], 4096,
                                           (const unsigned*)d_in[0], 16384, flag);
  SegTable t;
  int total = 0;
  for (int i = 0; i < 16; i++){
    t.src[i] = d_in[i];
    t.dst[i] = ptrs[i];
    t.cnt[i] = sizes[i];
    total += sizes[i];
  }
  t.total = total;
  decode_kernel_r15<<<(total + 255)/256, 256, 0, stream>>>(t, flag);

  const float* enc_w  = ptrs[2];  const float* enc_b  = ptrs[3];
  const float* g1_ws  = ptrs[4];  const float* g1_wn  = ptrs[5];
  const float* g1_g   = ptrs[6];  const float* g1_b   = ptrs[7];
  const float* g2_ws  = ptrs[8];  const float* g2_wn  = ptrs[9];
  const float* g2_g   = ptrs[10]; const float* g2_b   = ptrs[11];
  const float* cls_w1 = ptrs[12]; const float* cls_b1 = ptrs[13];
  const float* cls_w2 = ptrs[14]; const float* cls_b2 = ptrs[15];

  dim3 b256(256);
  // knn pre-pass: bucket counting sort by x (+ zero outlier counter)
  zero_kernel_r15<<<(NB + 255)/256, b256, 0, stream>>>(hist, cursor, ocnt);
  count_kernel_r15<<<(NND + 255)/256, b256, 0, stream>>>(C, hist);
  scan_kernel_r15<<<1, 1024, 0, stream>>>(hist, offs);
  scatter_kernel_r15<<<(NND + 255)/256, b256, 0, stream>>>(C, offs, cursor, sxy, sid);
  // encoder: h = gelu(feats @ enc_w^T + enc_b)
  mm_kernel_r15<256,false,true><<<NND/32, b256, 0, stream>>>(F, nullptr, enc_w, nullptr, enc_b, h);
  // knn: fixed-window wave-per-node + bounded rescan for deferred nodes
  knn_fixed_r15<<<NND/4, b256, 0, stream>>>(sxy, sid, C, offs, gidx, gw, ocnt, olist, othr);
  knn_ext_r15<<<512, b256, 0, stream>>>(sxy, sid, C, offs, olist, othr, ocnt, gidx, gw);
  // sage layer 1 (tmp := F, feats dead after encoder)
  agg_kernel_r15<<<NND/4, b256, 0, stream>>>(h, gidx, gw, agg);
  mm_kernel_r15<256,true,false><<<NND/32, b256, 0, stream>>>(h, agg, g1_ws, g1_wn, nullptr, F);
  ln_res_kernel_r15<<<NND/4, b256, 0, stream>>>(h, F, g1_g, g1_b);
  // sage layer 2
  agg_kernel_r15<<<NND/4, b256, 0, stream>>>(h, gidx, gw, agg);
  mm_kernel_r15<256,true,false><<<NND/32, b256, 0, stream>>>(h, agg, g2_ws, g2_wn, nullptr, F);
  ln_res_kernel_r15<<<NND/4, b256, 0, stream>>>(h, F, g2_g, g2_b);
  // classifier
  mm_kernel_r15<128,false,true><<<NND/32, b256, 0, stream>>>(h, nullptr, cls_w1, nullptr, cls_b1, hid);
  cls2_kernel_r15<<<NND/4, b256, 0, stream>>>(hid, cls_w2, cls_b2, d_out, flag);
}

// Round 16
// 563.140 us; speedup vs baseline: 1.6020x; 1.0107x over previous
//
#include <hip/hip_runtime.h>
#include <hip/hip_bf16.h>
#include <stdint.h>

#define NND 12000
#define DM  256
#define KNN 16
#define NB  4096          // x-buckets
#define BW  0.00390625f   // bucket width = 1/256 over [-8, 8)
#define RW  16            // fixed-window rounds (16*64 = 1024 candidates)

// Opaque register barrier: prevents FMA contraction (r9: made knn bit-match numpy
// -> absmax 0.0. DO NOT REMOVE).
#define FPBAR(x) asm volatile("" : "+v"(x))

typedef unsigned long long u64;

__device__ __forceinline__ float geluf(float x){ return 0.5f*x*(1.0f + erff(x*0.70710678118654752f)); }
__device__ __forceinline__ int bucketof(float x){
  int b = (int)floorf((x + 8.0f) * 256.0f);
  return min(max(b, 0), NB-1);
}

// bit-exact numpy distance key (r9-verified). Low 32 bits = original node idx.
__device__ __forceinline__ u64 make_key(float xi, float yi, float sqi,
                                        float cx, float cy, int jd, int self){
  float ax = cx*cx;  FPBAR(ax);
  float ay = cy*cy;  FPBAR(ay);
  float sqj = ax + ay;   FPBAR(sqj);
  float px = xi*cx;    FPBAR(px);
  float py = yi*cy;    FPBAR(py);
  float dt = px + py;    FPBAR(dt);            // NO-FMA dot
  float two_dt = 2.0f*dt;  FPBAR(two_dt);
  float ss = sqi + sqj;    FPBAR(ss);
  float d2 = ss - two_dt;  FPBAR(d2);
  float dist = __fsqrt_rn(fmaxf(d2, 0.0f));
  u64 key = ((u64)__float_as_uint(dist) << 32) | (unsigned)jd;
  return (jd == self) ? ~0ULL : key;
}

// branchless sorted top-16 insert (ascending u64 keys)
__device__ __forceinline__ void ladder_insert(u64* L, u64 key){
  bool c[KNN];
  #pragma unroll
  for (int t=0;t<KNN;t++) c[t] = key < L[t];
  #pragma unroll
  for (int t=KNN-1;t>=1;t--) L[t] = c[t-1] ? L[t-1] : (c[t] ? key : L[t]);
  L[0] = c[0] ? key : L[0];
}

// wave-level 64-list tournament merge; lane r gets r-th smallest of the union.
__device__ __forceinline__ u64 wave_merge16(u64* slice, int lane, const u64* L)
{
  #pragma unroll
  for (int t=0;t<KNN;t++) slice[t*64 + lane] = L[t];
  int p = 0;
  u64 cur = slice[lane];
  u64 out16 = ~0ULL;
  for (int r=0;r<KNN;r++){
    u64 k = cur; int who = lane;
    #pragma unroll
    for (int o=32;o>0;o>>=1){
      u64 ok = __shfl_xor(k, o, 64);
      int ow = __shfl_xor(who, o, 64);
      if (ok < k){ k = ok; who = ow; }
    }
    if (lane == r) out16 = k;
    if (lane == who){
      ++p;
      cur = (p < KNN) ? slice[p*64 + lane] : ~0ULL;
    }
  }
  return out16;
}

// shared epilogue: weights via numpy pairwise tree (bit-exact since r9)
__device__ __forceinline__ void write_outputs(u64 out16, int lane, int n,
    int* __restrict__ idx_out, float* __restrict__ w_out)
{
  if (lane < KNN) idx_out[(size_t)n*KNN + lane] = (int)(unsigned)(out16 & 0xFFFFFFFFull);
  u64 kt[KNN];
  #pragma unroll
  for (int t=0;t<KNN;t++) kt[t] = __shfl(out16, t, 64);
  float inv[KNN];
  #pragma unroll
  for (int t=0;t<KNN;t++){
    float d = __uint_as_float((unsigned)(kt[t] >> 32));
    inv[t] = __fdiv_rn(1.0f, fmaxf(d, 1e-4f));
  }
  float r8v[8];
  #pragma unroll
  for (int t=0;t<8;t++){ r8v[t] = inv[t] + inv[t+8]; FPBAR(r8v[t]); }
  float s01 = r8v[0]+r8v[1]; FPBAR(s01);
  float s23 = r8v[2]+r8v[3]; FPBAR(s23);
  float s45 = r8v[4]+r8v[5]; FPBAR(s45);
  float s67 = r8v[6]+r8v[7]; FPBAR(s67);
  float sA = s01+s23; FPBAR(sA);
  float sB = s45+s67; FPBAR(sB);
  float s = sA + sB;
  s = fmaxf(s, 1e-8f);
  if (lane < KNN){
    float d = __uint_as_float((unsigned)(out16 >> 32));
    float invL = __fdiv_rn(1.0f, fmaxf(d, 1e-4f));
    w_out[(size_t)n*KNN + lane] = __fdiv_rn(invL, s);
  }
}

// ---------------- dtype detection (proven: picks f32 here) ----------------
__global__ __launch_bounds__(256) void detect_kernel_r16(
    const unsigned* __restrict__ a, int na,
    const unsigned* __restrict__ b, int nb, int* __restrict__ flag)
{
  __shared__ int cnt;
  if (threadIdx.x == 0) cnt = 0;
  __syncthreads();
  int c = 0;
  for (int i = threadIdx.x; i < na; i += 256){
    int ex = (a[i] >> 7) & 0xFF;
    c += (ex >= 113 && ex <= 131) ? 1 : 0;
  }
  for (int i = threadIdx.x; i < nb; i += 256){
    int ex = (b[i] >> 7) & 0xFF;
    c += (ex >= 113 && ex <= 131) ? 1 : 0;
  }
  atomicAdd(&cnt, c);
  __syncthreads();
  if (threadIdx.x == 0) *flag = (cnt > (na + nb) / 2) ? 1 : 0;
}

// ---------------- decode all inputs to f32 workspace ----------------
struct SegTable {
  const void* src[16];
  float*      dst[16];
  int         cnt[16];
  int         total;
};

__global__ __launch_bounds__(256) void decode_kernel_r16(SegTable t, const int* __restrict__ flag)
{
  const int is_bf16 = *flag;
  for (int e = blockIdx.x*256 + threadIdx.x; e < t.total; e += gridDim.x*256){
    int rem = e, s = 0;
    while (rem >= t.cnt[s]){ rem -= t.cnt[s]; ++s; }
    float v;
    if (is_bf16) v = __uint_as_float(((unsigned)((const unsigned short*)t.src[s])[rem]) << 16);
    else         v = ((const float*)t.src[s])[rem];
    t.dst[s][rem] = v;
  }
}

// ---------------- bucket pre-pass ----------------
__global__ __launch_bounds__(256) void zero_kernel_r16(int* __restrict__ hist, int* __restrict__ cursor,
                                                       int* __restrict__ ocnt)
{
  int t = blockIdx.x*256 + threadIdx.x;
  if (t < NB){ hist[t] = 0; cursor[t] = 0; }
  if (blockIdx.x == 0 && threadIdx.x == 0) *ocnt = 0;
}

__global__ __launch_bounds__(256) void count_kernel_r16(const float* __restrict__ cents,
                                                        int* __restrict__ hist)
{
  int i = blockIdx.x*256 + threadIdx.x;
  if (i < NND) atomicAdd(&hist[bucketof(cents[2*i])], 1);
}

__global__ __launch_bounds__(1024) void scan_kernel_r16(const int* __restrict__ hist,
                                                        int* __restrict__ offs)
{
  __shared__ int s[1024];
  int t = threadIdx.x;
  int h0 = hist[t*4], h1 = hist[t*4+1], h2 = hist[t*4+2], h3 = hist[t*4+3];
  int tot = h0+h1+h2+h3;
  s[t] = tot;
  __syncthreads();
  for (int d=1; d<1024; d<<=1){
    int v = (t >= d) ? s[t-d] : 0;
    __syncthreads();
    s[t] += v;
    __syncthreads();
  }
  int excl = s[t] - tot;
  offs[t*4]   = excl;
  offs[t*4+1] = excl + h0;
  offs[t*4+2] = excl + h0 + h1;
  offs[t*4+3] = excl + h0 + h1 + h2;
}

__global__ __launch_bounds__(256) void scatter_kernel_r16(const float* __restrict__ cents,
    const int* __restrict__ offs, int* __restrict__ cursor,
    float2* __restrict__ sxy, int* __restrict__ sid)
{
  int i = blockIdx.x*256 + threadIdx.x;
  if (i < NND){
    float x = cents[2*i], y = cents[2*i+1];
    int b = bucketof(x);
    int pos = offs[b] + atomicAdd(&cursor[b], 1);
    sxy[pos] = make_float2(x, y);
    sid[pos] = i;
  }
}

// ---------------- kNN: fixed 1024-window per node + post-hoc check (r15-verified) ----------------
__global__ __launch_bounds__(256) void knn_fixed_r16(
    const float2* __restrict__ sxy, const int* __restrict__ sid,
    const float* __restrict__ cents, const int* __restrict__ offs,
    int* __restrict__ idx_out, float* __restrict__ w_out,
    int* __restrict__ ocnt, int* __restrict__ olist, float* __restrict__ othr)
{
  __shared__ u64 lds_k[4][KNN*64];   // 32 KB
  const int lane = threadIdx.x & 63, wv = threadIdx.x >> 6;
  const int n = blockIdx.x*4 + wv;
  const float xi = cents[2*n];
  const float yi = cents[2*n+1];
  float sx = xi*xi; FPBAR(sx);
  float sy = yi*yi; FPBAR(sy);
  float sqi = sx + sy; FPBAR(sqi);

  const int start = offs[bucketof(xi)];
  const bool isR = lane < 32;
  const int lo = isR ? lane : (lane - 32);

  u64 L[KNN];
  #pragma unroll
  for (int t=0;t<KNN;t++) L[t] = ~0ULL;

  #pragma unroll 2
  for (int r=0;r<RW;r++){
    int myp = isR ? (start + r*32 + lo) : (start - 1 - r*32 - lo);
    bool act = (myp >= 0) && (myp < NND);
    float2 cu = make_float2(0.f, 0.f);
    int jd = -1;
    if (act){ cu = sxy[myp]; jd = sid[myp]; }
    u64 key = make_key(xi, yi, sqi, cu.x, cu.y, jd, n);
    if (!act) key = ~0ULL;
    ladder_insert(L, key);
  }

  u64 out16 = wave_merge16(&lds_k[wv][0], lane, L);
  float B = __uint_as_float((unsigned)(__shfl(out16, KNN-1, 64) >> 32));
  const float thr = B*B + 2e-4f;

  const int qr = min(start + RW*32, NND);
  const int ql = max(start - RW*32, 0);
  bool ok;
  {
    bool rok = (qr >= NND);
    if (!rok){
      float xR = sxy[qr-1].x;
      float dxr = ((float)bucketof(xR)*BW - 8.0f) - xi;
      rok = (dxr > 0.0f) && (dxr*dxr > thr);
    }
    bool lok = (ql <= 0);
    if (!lok){
      float xL = sxy[ql].x;
      float dxl = xi - ((float)(bucketof(xL)+1)*BW - 8.0f);
      lok = (dxl > 0.0f) && (dxl*dxl > thr);
    }
    ok = rok && lok;
  }
  if (lane == 0 && !ok){
    int s = atomicAdd(ocnt, 1);
    olist[s] = n;
    othr[s] = thr;
  }

  write_outputs(out16, lane, n, idx_out, w_out);
}

// ---------------- bounded rescan for deferred nodes (r15-verified, exact) ----------------
__global__ __launch_bounds__(256) void knn_ext_r16(
    const float2* __restrict__ sxy, const int* __restrict__ sid,
    const float* __restrict__ cents, const int* __restrict__ offs,
    const int* __restrict__ olist, const float* __restrict__ othr,
    const int* __restrict__ ocnt,
    int* __restrict__ idx_out, float* __restrict__ w_out)
{
  __shared__ u64 lds_k[4][KNN*64];   // 32 KB
  const int lane = threadIdx.x & 63, wv = threadIdx.x >> 6;
  const int cnt = *ocnt;

  for (int slot = blockIdx.x*4 + wv; slot < cnt; slot += gridDim.x*4){
    const int n = olist[slot];
    const float thr = othr[slot];
    const float rB = __fsqrt_rn(thr) * (1.0f + 2e-6f);
    const float xi = cents[2*n];
    const float yi = cents[2*n+1];
    float sx = xi*xi; FPBAR(sx);
    float sy = yi*yi; FPBAR(sy);
    float sqi = sx + sy; FPBAR(sqi);

    const int bL = bucketof(xi - rB);
    const int bR = bucketof(xi + rB);
    const int posL = offs[bL];
    const int posR = (bR + 1 < NB) ? offs[bR + 1] : NND;

    u64 L[KNN];
    #pragma unroll
    for (int t=0;t<KNN;t++) L[t] = ~0ULL;

    for (int p = posL + lane; p < posR; p += 64){
      float2 cu = sxy[p];
      ladder_insert(L, make_key(xi, yi, sqi, cu.x, cu.y, sid[p], n));
    }

    u64 out16 = wave_merge16(&lds_k[wv][0], lane, L);
    write_outputs(out16, lane, n, idx_out, w_out);
  }
}

// ---------------- GEMM: C[M,OUT] = gelu(A1@W1^T (+ A2@W2^T) (+ bias)) ----------------
// r16: 2-D tile split for occupancy. TM=16 rows, COLS cols per block ->
// grid (NND/16, OUT/COLS) = 1500 blocks for OUT=256 (vs 375 in r15: Occupancy
// was 13%, VALUBusy 43% -- grid starvation). W-LDS halves to ~10 KB per matrix.
// Per-output K-accumulation order identical to r15 -> bit-identical results.
template<int OUT, int COLS, bool DUAL, bool BIAS>
__global__ __launch_bounds__(256) void mm_kernel_r16(
    const float* __restrict__ A1, const float* __restrict__ A2,
    const float* __restrict__ W1, const float* __restrict__ W2,
    const float* __restrict__ bias, float* __restrict__ C)
{
  constexpr int KC = 16;
  constexpr int TM = 16;
  constexpr int WS = KC + 4;      // 20 floats: rows 16B-aligned for float4 reads
  constexpr int NQ = COLS / 64;
  __shared__ float Wl1[COLS*WS];
  __shared__ float Wl2[DUAL ? COLS*WS : 1];
  __shared__ float Al1[TM*KC];
  __shared__ float Al2[DUAL ? TM*KC : 1];

  const int tid = threadIdx.x;
  const int cg  = tid & 63;
  const int rg  = tid >> 6;
  const int m0  = blockIdx.x * TM;
  const int colbase = blockIdx.y * COLS;

  float acc[4][NQ];
  #pragma unroll
  for (int r=0;r<4;r++)
    #pragma unroll
    for (int q=0;q<NQ;q++) acc[r][q] = 0.f;

  for (int c0=0; c0<DM; c0+=KC){
    for (int e=tid; e < COLS*(KC/4); e += 256){
      int row = e >> 2;
      int c4  = (e & 3)*4;
      *(float4*)&Wl1[row*WS + c4] = *(const float4*)(W1 + (size_t)(colbase+row)*DM + c0 + c4);
      if (DUAL)
        *(float4*)&Wl2[row*WS + c4] = *(const float4*)(W2 + (size_t)(colbase+row)*DM + c0 + c4);
    }
    for (int e=tid; e < TM*(KC/4); e += 256){
      int row = e >> 2;
      int c4  = (e & 3)*4;
      size_t gi = (size_t)(m0+row)*DM + c0 + c4;
      *(float4*)&Al1[row*KC+c4] = *(const float4*)(A1 + gi);
      if (DUAL) *(float4*)&Al2[row*KC+c4] = *(const float4*)(A2 + gi);
    }
    __syncthreads();
    #pragma unroll
    for (int k4=0; k4<KC/4; k4++){
      float4 wv1[NQ]; float4 wv2[NQ];
      #pragma unroll
      for (int q=0;q<NQ;q++){
        wv1[q] = *(const float4*)&Wl1[(cg+64*q)*WS + k4*4];
        if (DUAL) wv2[q] = *(const float4*)&Wl2[(cg+64*q)*WS + k4*4];
      }
      #pragma unroll
      for (int r=0;r<4;r++){
        float4 a1 = *(const float4*)&Al1[(rg*4+r)*KC + k4*4];   // wave-uniform broadcast
        float4 a2;
        if (DUAL) a2 = *(const float4*)&Al2[(rg*4+r)*KC + k4*4];
        #pragma unroll
        for (int q=0;q<NQ;q++){
          float s = acc[r][q];
          s = fmaf(a1.x, wv1[q].x, s);
          s = fmaf(a1.y, wv1[q].y, s);
          s = fmaf(a1.z, wv1[q].z, s);
          s = fmaf(a1.w, wv1[q].w, s);
          if (DUAL){
            s = fmaf(a2.x, wv2[q].x, s);
            s = fmaf(a2.y, wv2[q].y, s);
            s = fmaf(a2.z, wv2[q].z, s);
            s = fmaf(a2.w, wv2[q].w, s);
          }
          acc[r][q] = s;
        }
      }
    }
    __syncthreads();
  }
  #pragma unroll
  for (int q=0;q<NQ;q++){
    int d = colbase + cg + 64*q;
    float bv = BIAS ? bias[d] : 0.f;
    #pragma unroll
    for (int r=0;r<4;r++){
      float v = geluf(acc[r][q] + bv);
      C[(size_t)(m0 + rg*4 + r)*OUT + d] = v;
    }
  }
}

// ---------------- weighted neighbor aggregation ----------------
__global__ __launch_bounds__(256) void agg_kernel_r16(const float* __restrict__ h,
    const int* __restrict__ idx, const float* __restrict__ w, float* __restrict__ agg)
{
  const int lane = threadIdx.x & 63, wid = threadIdx.x >> 6;
  const int n = blockIdx.x*4 + wid;
  const int base = n*KNN;
  float4 acc = make_float4(0.f,0.f,0.f,0.f);
  for (int k=0;k<KNN;k++){
    int j = idx[base+k];
    float wk = w[base+k];
    float4 hv = *(const float4*)(h + (size_t)j*DM + lane*4);
    acc.x = fmaf(wk, hv.x, acc.x);
    acc.y = fmaf(wk, hv.y, acc.y);
    acc.z = fmaf(wk, hv.z, acc.z);
    acc.w = fmaf(wk, hv.w, acc.w);
  }
  *(float4*)(agg + (size_t)n*DM + lane*4) = acc;
}

// ---------------- h = h + layernorm(tmp)*g + b ----------------
__global__ __launch_bounds__(256) void ln_res_kernel_r16(float* __restrict__ h,
    const float* __restrict__ tmp, const float* __restrict__ g, const float* __restrict__ b)
{
  const int lane = threadIdx.x & 63, wid = threadIdx.x >> 6;
  const int n = blockIdx.x*4 + wid;
  float4 x = *(const float4*)(tmp + (size_t)n*DM + lane*4);
  float s = (x.x + x.y) + (x.z + x.w);
  #pragma unroll
  for (int off=32; off>0; off>>=1) s += __shfl_xor(s, off, 64);
  float mu = s * (1.0f/DM);
  float dx0 = x.x-mu, dx1 = x.y-mu, dx2 = x.z-mu, dx3 = x.w-mu;
  float v = (dx0*dx0 + dx1*dx1) + (dx2*dx2 + dx3*dx3);
  #pragma unroll
  for (int off=32; off>0; off>>=1) v += __shfl_xor(v, off, 64);
  float rs = 1.0f / sqrtf(v * (1.0f/DM) + 1e-5f);
  int c = lane*4;
  float4 gv = *(const float4*)(g + c);
  float4 bv = *(const float4*)(b + c);
  float4 hv = *(const float4*)(h + (size_t)n*DM + c);
  hv.x += dx0*rs*gv.x + bv.x;
  hv.y += dx1*rs*gv.y + bv.y;
  hv.z += dx2*rs*gv.z + bv.z;
  hv.w += dx3*rs*gv.w + bv.w;
  *(float4*)(h + (size_t)n*DM + c) = hv;
}

// ---------------- final: out[n] = sigmoid(dot(hid[n], w2) + b2), dtype per flag ----------------
__global__ __launch_bounds__(256) void cls2_kernel_r16(const float* __restrict__ hid,
    const float* __restrict__ w2, const float* __restrict__ b2,
    void* __restrict__ out, const int* __restrict__ flag)
{
  const int lane = threadIdx.x & 63, wid = threadIdx.x >> 6;
  const int n = blockIdx.x*4 + wid;
  float a = hid[(size_t)n*128 + lane]      * w2[lane]
          + hid[(size_t)n*128 + 64 + lane] * w2[64+lane];
  #pragma unroll
  for (int off=32; off>0; off>>=1) a += __shfl_xor(a, off, 64);
  if (lane == 0){
    float v = 1.0f / (1.0f + expf(-(a + b2[0])));
    if (*flag) ((__hip_bfloat16*)out)[n] = __float2bfloat16(v);
    else       ((float*)out)[n] = v;
  }
}

extern "C" void kernel_launch(void* const* d_in, const int* in_sizes, int n_in,
                              void* d_out, int out_size, void* d_ws, size_t ws_size,
                              hipStream_t stream)
{
  // ---- workspace layout (~45 MB), fully rewritten every call ----
  char* base = (char*)d_ws;
  int*   flag = (int*)base;                                   // 16 B slot
  float* wreg = (float*)(base + 16);
  static const int sizes[16] = {
    NND*256, NND*2, 256*256, 256, 256*256, 256*256, 256, 256,
    256*256, 256*256, 256, 256, 128*256, 128, 128, 1
  };
  float* ptrs[16];
  {
    float* p = wreg;
    for (int i = 2; i < 16; i++){ ptrs[i] = p; p += sizes[i]; }
    ptrs[1] = p;                          // cents  [24,000]
    p += NND*2;
    ptrs[0] = p;                          // feats  [3,072,000]  (reused as tmp later)
  }
  float* F    = ptrs[0];
  float* C    = ptrs[1];
  float* h    = F + (size_t)NND*DM;
  float* agg  = h + (size_t)NND*DM;
  float* hid  = agg + (size_t)NND*DM;
  int*  gidx  = (int*)(hid + (size_t)NND*128);
  float* gw   = (float*)(gidx + (size_t)NND*KNN);
  // knn pre-pass scratch
  float2* sxy   = (float2*)(gw + (size_t)NND*KNN);
  int*    sid   = (int*)(sxy + NND);
  int*    hist  = sid + NND;
  int*    cursor= hist + NB;
  int*    offs  = cursor + NB;
  int*    ocnt  = offs + NB;
  int*    olist = ocnt + 1;               // up to 12000 ints
  float*  othr  = (float*)(olist + NND);  // thr per deferred node

  // ---- dtype detect + decode ----
  detect_kernel_r16<<<1, 256, 0, stream>>>((const unsigned*)d_in[1], 4096,
                                           (const unsigned*)d_in[0], 16384, flag);
  SegTable t;
  int total = 0;
  for (int i = 0; i < 16; i++){
    t.src[i] = d_in[i];
    t.dst[i] = ptrs[i];
    t.cnt[i] = sizes[i];
    total += sizes[i];
  }
  t.total = total;
  decode_kernel_r16<<<(total + 255)/256, 256, 0, stream>>>(t, flag);

  const float* enc_w  = ptrs[2];  const float* enc_b  = ptrs[3];
  const float* g1_ws  = ptrs[4];  const float* g1_wn  = ptrs[5];
  const float* g1_g   = ptrs[6];  const float* g1_b   = ptrs[7];
  const float* g2_ws  = ptrs[8];  const float* g2_wn  = ptrs[9];
  const float* g2_g   = ptrs[10]; const float* g2_b   = ptrs[11];
  const float* cls_w1 = ptrs[12]; const float* cls_b1 = ptrs[13];
  const float* cls_w2 = ptrs[14]; const float* cls_b2 = ptrs[15];

  dim3 b256(256);
  // knn pre-pass: bucket counting sort by x (+ zero outlier counter)
  zero_kernel_r16<<<(NB + 255)/256, b256, 0, stream>>>(hist, cursor, ocnt);
  count_kernel_r16<<<(NND + 255)/256, b256, 0, stream>>>(C, hist);
  scan_kernel_r16<<<1, 1024, 0, stream>>>(hist, offs);
  scatter_kernel_r16<<<(NND + 255)/256, b256, 0, stream>>>(C, offs, cursor, sxy, sid);
  // encoder: h = gelu(feats @ enc_w^T + enc_b)
  mm_kernel_r16<256,128,false,true><<<dim3(NND/16, 2), b256, 0, stream>>>(F, nullptr, enc_w, nullptr, enc_b, h);
  // knn: fixed-window wave-per-node + bounded rescan for deferred nodes
  knn_fixed_r16<<<NND/4, b256, 0, stream>>>(sxy, sid, C, offs, gidx, gw, ocnt, olist, othr);
  knn_ext_r16<<<512, b256, 0, stream>>>(sxy, sid, C, offs, olist, othr, ocnt, gidx, gw);
  // sage layer 1 (tmp := F, feats dead after encoder)
  agg_kernel_r16<<<NND/4, b256, 0, stream>>>(h, gidx, gw, agg);
  mm_kernel_r16<256,128,true,false><<<dim3(NND/16, 2), b256, 0, stream>>>(h, agg, g1_ws, g1_wn, nullptr, F);
  ln_res_kernel_r16<<<NND/4, b256, 0, stream>>>(h, F, g1_g, g1_b);
  // sage layer 2
  agg_kernel_r16<<<NND/4, b256, 0, stream>>>(h, gidx, gw, agg);
  mm_kernel_r16<256,128,true,false><<<dim3(NND/16, 2), b256, 0, stream>>>(h, agg, g2_ws, g2_wn, nullptr, F);
  ln_res_kernel_r16<<<NND/4, b256, 0, stream>>>(h, F, g2_g, g2_b);
  // classifier
  mm_kernel_r16<128,128,false,true><<<dim3(NND/16, 1), b256, 0, stream>>>(h, nullptr, cls_w1, nullptr, cls_b1, hid);
  cls2_kernel_r16<<<NND/4, b256, 0, stream>>>(hid, cls_w2, cls_b2, d_out, flag);
}

// Round 17
// 523.262 us; speedup vs baseline: 1.7241x; 1.0762x over previous
//
#include <hip/hip_runtime.h>
#include <hip/hip_bf16.h>
#include <stdint.h>

#define NND 12000
#define DM  256
#define KNN 16
#define NB  4096          // x-buckets
#define BW  0.00390625f   // bucket width = 1/256 over [-8, 8)
#define RW  16            // fixed-window rounds (16*64 = 1024 candidates)

// Opaque register barrier: prevents FMA contraction (r9: made knn bit-match numpy
// -> absmax 0.0. DO NOT REMOVE).
#define FPBAR(x) asm volatile("" : "+v"(x))

typedef unsigned long long u64;

__device__ __forceinline__ float geluf(float x){ return 0.5f*x*(1.0f + erff(x*0.70710678118654752f)); }
__device__ __forceinline__ int bucketof(float x){
  int b = (int)floorf((x + 8.0f) * 256.0f);
  return min(max(b, 0), NB-1);
}

// bit-exact numpy distance key (r9-verified). Low 32 bits = original node idx.
__device__ __forceinline__ u64 make_key(float xi, float yi, float sqi,
                                        float cx, float cy, int jd, int self){
  float ax = cx*cx;  FPBAR(ax);
  float ay = cy*cy;  FPBAR(ay);
  float sqj = ax + ay;   FPBAR(sqj);
  float px = xi*cx;    FPBAR(px);
  float py = yi*cy;    FPBAR(py);
  float dt = px + py;    FPBAR(dt);            // NO-FMA dot
  float two_dt = 2.0f*dt;  FPBAR(two_dt);
  float ss = sqi + sqj;    FPBAR(ss);
  float d2 = ss - two_dt;  FPBAR(d2);
  float dist = __fsqrt_rn(fmaxf(d2, 0.0f));
  u64 key = ((u64)__float_as_uint(dist) << 32) | (unsigned)jd;
  return (jd == self) ? ~0ULL : key;
}

// branchless sorted top-16 insert (ascending u64 keys)
__device__ __forceinline__ void ladder_insert(u64* L, u64 key){
  bool c[KNN];
  #pragma unroll
  for (int t=0;t<KNN;t++) c[t] = key < L[t];
  #pragma unroll
  for (int t=KNN-1;t>=1;t--) L[t] = c[t-1] ? L[t-1] : (c[t] ? key : L[t]);
  L[0] = c[0] ? key : L[0];
}

// wave-level 64-list tournament merge; lane r gets r-th smallest of the union.
__device__ __forceinline__ u64 wave_merge16(u64* slice, int lane, const u64* L)
{
  #pragma unroll
  for (int t=0;t<KNN;t++) slice[t*64 + lane] = L[t];
  int p = 0;
  u64 cur = slice[lane];
  u64 out16 = ~0ULL;
  for (int r=0;r<KNN;r++){
    u64 k = cur; int who = lane;
    #pragma unroll
    for (int o=32;o>0;o>>=1){
      u64 ok = __shfl_xor(k, o, 64);
      int ow = __shfl_xor(who, o, 64);
      if (ok < k){ k = ok; who = ow; }
    }
    if (lane == r) out16 = k;
    if (lane == who){
      ++p;
      cur = (p < KNN) ? slice[p*64 + lane] : ~0ULL;
    }
  }
  return out16;
}

// shared epilogue: weights via numpy pairwise tree (bit-exact since r9)
__device__ __forceinline__ void write_outputs(u64 out16, int lane, int n,
    int* __restrict__ idx_out, float* __restrict__ w_out)
{
  if (lane < KNN) idx_out[(size_t)n*KNN + lane] = (int)(unsigned)(out16 & 0xFFFFFFFFull);
  u64 kt[KNN];
  #pragma unroll
  for (int t=0;t<KNN;t++) kt[t] = __shfl(out16, t, 64);
  float inv[KNN];
  #pragma unroll
  for (int t=0;t<KNN;t++){
    float d = __uint_as_float((unsigned)(kt[t] >> 32));
    inv[t] = __fdiv_rn(1.0f, fmaxf(d, 1e-4f));
  }
  float r8v[8];
  #pragma unroll
  for (int t=0;t<8;t++){ r8v[t] = inv[t] + inv[t+8]; FPBAR(r8v[t]); }
  float s01 = r8v[0]+r8v[1]; FPBAR(s01);
  float s23 = r8v[2]+r8v[3]; FPBAR(s23);
  float s45 = r8v[4]+r8v[5]; FPBAR(s45);
  float s67 = r8v[6]+r8v[7]; FPBAR(s67);
  float sA = s01+s23; FPBAR(sA);
  float sB = s45+s67; FPBAR(sB);
  float s = sA + sB;
  s = fmaxf(s, 1e-8f);
  if (lane < KNN){
    float d = __uint_as_float((unsigned)(out16 >> 32));
    float invL = __fdiv_rn(1.0f, fmaxf(d, 1e-4f));
    w_out[(size_t)n*KNN + lane] = __fdiv_rn(invL, s);
  }
}

// ---------------- dtype detection (proven: picks f32 here) ----------------
__global__ __launch_bounds__(256) void detect_kernel_r17(
    const unsigned* __restrict__ a, int na,
    const unsigned* __restrict__ b, int nb, int* __restrict__ flag)
{
  __shared__ int cnt;
  if (threadIdx.x == 0) cnt = 0;
  __syncthreads();
  int c = 0;
  for (int i = threadIdx.x; i < na; i += 256){
    int ex = (a[i] >> 7) & 0xFF;
    c += (ex >= 113 && ex <= 131) ? 1 : 0;
  }
  for (int i = threadIdx.x; i < nb; i += 256){
    int ex = (b[i] >> 7) & 0xFF;
    c += (ex >= 113 && ex <= 131) ? 1 : 0;
  }
  atomicAdd(&cnt, c);
  __syncthreads();
  if (threadIdx.x == 0) *flag = (cnt > (na + nb) / 2) ? 1 : 0;
}

// ---------------- decode all inputs to f32 workspace ----------------
struct SegTable {
  const void* src[16];
  float*      dst[16];
  int         cnt[16];
  int         total;
};

__global__ __launch_bounds__(256) void decode_kernel_r17(SegTable t, const int* __restrict__ flag)
{
  const int is_bf16 = *flag;
  for (int e = blockIdx.x*256 + threadIdx.x; e < t.total; e += gridDim.x*256){
    int rem = e, s = 0;
    while (rem >= t.cnt[s]){ rem -= t.cnt[s]; ++s; }
    float v;
    if (is_bf16) v = __uint_as_float(((unsigned)((const unsigned short*)t.src[s])[rem]) << 16);
    else         v = ((const float*)t.src[s])[rem];
    t.dst[s][rem] = v;
  }
}

// ---------------- bucket pre-pass ----------------
__global__ __launch_bounds__(256) void zero_kernel_r17(int* __restrict__ hist, int* __restrict__ cursor,
                                                       int* __restrict__ ocnt)
{
  int t = blockIdx.x*256 + threadIdx.x;
  if (t < NB){ hist[t] = 0; cursor[t] = 0; }
  if (blockIdx.x == 0 && threadIdx.x == 0) *ocnt = 0;
}

__global__ __launch_bounds__(256) void count_kernel_r17(const float* __restrict__ cents,
                                                        int* __restrict__ hist)
{
  int i = blockIdx.x*256 + threadIdx.x;
  if (i < NND) atomicAdd(&hist[bucketof(cents[2*i])], 1);
}

__global__ __launch_bounds__(1024) void scan_kernel_r17(const int* __restrict__ hist,
                                                        int* __restrict__ offs)
{
  __shared__ int s[1024];
  int t = threadIdx.x;
  int h0 = hist[t*4], h1 = hist[t*4+1], h2 = hist[t*4+2], h3 = hist[t*4+3];
  int tot = h0+h1+h2+h3;
  s[t] = tot;
  __syncthreads();
  for (int d=1; d<1024; d<<=1){
    int v = (t >= d) ? s[t-d] : 0;
    __syncthreads();
    s[t] += v;
    __syncthreads();
  }
  int excl = s[t] - tot;
  offs[t*4]   = excl;
  offs[t*4+1] = excl + h0;
  offs[t*4+2] = excl + h0 + h1;
  offs[t*4+3] = excl + h0 + h1 + h2;
}

__global__ __launch_bounds__(256) void scatter_kernel_r17(const float* __restrict__ cents,
    const int* __restrict__ offs, int* __restrict__ cursor,
    float2* __restrict__ sxy, int* __restrict__ sid)
{
  int i = blockIdx.x*256 + threadIdx.x;
  if (i < NND){
    float x = cents[2*i], y = cents[2*i+1];
    int b = bucketof(x);
    int pos = offs[b] + atomicAdd(&cursor[b], 1);
    sxy[pos] = make_float2(x, y);
    sid[pos] = i;
  }
}

// ---------------- kNN: fixed 1024-window per node + post-hoc check (r15-verified) ----------------
__global__ __launch_bounds__(256) void knn_fixed_r17(
    const float2* __restrict__ sxy, const int* __restrict__ sid,
    const float* __restrict__ cents, const int* __restrict__ offs,
    int* __restrict__ idx_out, float* __restrict__ w_out,
    int* __restrict__ ocnt, int* __restrict__ olist, float* __restrict__ othr)
{
  __shared__ u64 lds_k[4][KNN*64];   // 32 KB
  const int lane = threadIdx.x & 63, wv = threadIdx.x >> 6;
  const int n = blockIdx.x*4 + wv;
  const float xi = cents[2*n];
  const float yi = cents[2*n+1];
  float sx = xi*xi; FPBAR(sx);
  float sy = yi*yi; FPBAR(sy);
  float sqi = sx + sy; FPBAR(sqi);

  const int start = offs[bucketof(xi)];
  const bool isR = lane < 32;
  const int lo = isR ? lane : (lane - 32);

  u64 L[KNN];
  #pragma unroll
  for (int t=0;t<KNN;t++) L[t] = ~0ULL;

  #pragma unroll 2
  for (int r=0;r<RW;r++){
    int myp = isR ? (start + r*32 + lo) : (start - 1 - r*32 - lo);
    bool act = (myp >= 0) && (myp < NND);
    float2 cu = make_float2(0.f, 0.f);
    int jd = -1;
    if (act){ cu = sxy[myp]; jd = sid[myp]; }
    u64 key = make_key(xi, yi, sqi, cu.x, cu.y, jd, n);
    if (!act) key = ~0ULL;
    ladder_insert(L, key);
  }

  u64 out16 = wave_merge16(&lds_k[wv][0], lane, L);
  float B = __uint_as_float((unsigned)(__shfl(out16, KNN-1, 64) >> 32));
  const float thr = B*B + 2e-4f;

  const int qr = min(start + RW*32, NND);
  const int ql = max(start - RW*32, 0);
  bool ok;
  {
    bool rok = (qr >= NND);
    if (!rok){
      float xR = sxy[qr-1].x;
      float dxr = ((float)bucketof(xR)*BW - 8.0f) - xi;
      rok = (dxr > 0.0f) && (dxr*dxr > thr);
    }
    bool lok = (ql <= 0);
    if (!lok){
      float xL = sxy[ql].x;
      float dxl = xi - ((float)(bucketof(xL)+1)*BW - 8.0f);
      lok = (dxl > 0.0f) && (dxl*dxl > thr);
    }
    ok = rok && lok;
  }
  if (lane == 0 && !ok){
    int s = atomicAdd(ocnt, 1);
    olist[s] = n;
    othr[s] = thr;
  }

  write_outputs(out16, lane, n, idx_out, w_out);
}

// ---------------- bounded rescan for deferred nodes (r15-verified, exact) ----------------
__global__ __launch_bounds__(256) void knn_ext_r17(
    const float2* __restrict__ sxy, const int* __restrict__ sid,
    const float* __restrict__ cents, const int* __restrict__ offs,
    const int* __restrict__ olist, const float* __restrict__ othr,
    const int* __restrict__ ocnt,
    int* __restrict__ idx_out, float* __restrict__ w_out)
{
  __shared__ u64 lds_k[4][KNN*64];   // 32 KB
  const int lane = threadIdx.x & 63, wv = threadIdx.x >> 6;
  const int cnt = *ocnt;

  for (int slot = blockIdx.x*4 + wv; slot < cnt; slot += gridDim.x*4){
    const int n = olist[slot];
    const float thr = othr[slot];
    const float rB = __fsqrt_rn(thr) * (1.0f + 2e-6f);
    const float xi = cents[2*n];
    const float yi = cents[2*n+1];
    float sx = xi*xi; FPBAR(sx);
    float sy = yi*yi; FPBAR(sy);
    float sqi = sx + sy; FPBAR(sqi);

    const int bL = bucketof(xi - rB);
    const int bR = bucketof(xi + rB);
    const int posL = offs[bL];
    const int posR = (bR + 1 < NB) ? offs[bR + 1] : NND;

    u64 L[KNN];
    #pragma unroll
    for (int t=0;t<KNN;t++) L[t] = ~0ULL;

    for (int p = posL + lane; p < posR; p += 64){
      float2 cu = sxy[p];
      ladder_insert(L, make_key(xi, yi, sqi, cu.x, cu.y, sid[p], n));
    }

    u64 out16 = wave_merge16(&lds_k[wv][0], lane, L);
    write_outputs(out16, lane, n, idx_out, w_out);
  }
}

// ---------------- GEMM: C[M,OUT] = gelu(A1@W1^T (+ A2@W2^T) (+ bias)) ----------------
// r17: TM=32 rows x COLS=128 cols per block (r15's FMA:LDS ratio, r16's grid count:
// grid (375,2)=750 blocks) + register-level software pipeline: chunk c0+1's W/A
// global loads issue before chunk c0's compute, hiding global latency under the
// ~2048-cyc FMA phase. LDS stays single-buffered (24.5 KB -> 6 blocks/CU capacity).
// Per-output K-accumulation order (c0 asc, k4 asc, xyzw, a1-then-a2) identical to
// r15/r16 -> bit-identical outputs.
template<int OUT, int COLS, bool DUAL, bool BIAS>
__global__ __launch_bounds__(256) void mm_kernel_r17(
    const float* __restrict__ A1, const float* __restrict__ A2,
    const float* __restrict__ W1, const float* __restrict__ W2,
    const float* __restrict__ bias, float* __restrict__ C)
{
  constexpr int KC = 16;
  constexpr int TM = 32;
  constexpr int WS = KC + 4;      // 20 floats: rows 16B-aligned for float4 reads
  constexpr int NQ = COLS / 64;   // 2
  __shared__ float Wl1[COLS*WS];
  __shared__ float Wl2[DUAL ? COLS*WS : 1];
  __shared__ float Al1[TM*KC];
  __shared__ float Al2[DUAL ? TM*KC : 1];

  const int tid = threadIdx.x;
  const int cg  = tid & 63;
  const int rg  = tid >> 6;
  const int m0  = blockIdx.x * TM;
  const int colbase = blockIdx.y * COLS;

  // static staging jobs: W = COLS*KC/4 = 512 float4 -> 2/thread; A = 128 -> threads 0-127
  const int wrow0 = tid >> 2,          wc40 = (tid & 3)*4;
  const int wrow1 = (tid+256) >> 2,    wc41 = ((tid+256) & 3)*4;
  const bool hasA = tid < TM*4;
  const int arow = tid >> 2,           ac4  = (tid & 3)*4;

  float4 w1r0, w1r1, w2r0, w2r1, a1r, a2r;

  auto load_chunk = [&](int c0){
    w1r0 = *(const float4*)(W1 + (size_t)(colbase+wrow0)*DM + c0 + wc40);
    w1r1 = *(const float4*)(W1 + (size_t)(colbase+wrow1)*DM + c0 + wc41);
    if (DUAL){
      w2r0 = *(const float4*)(W2 + (size_t)(colbase+wrow0)*DM + c0 + wc40);
      w2r1 = *(const float4*)(W2 + (size_t)(colbase+wrow1)*DM + c0 + wc41);
    }
    if (hasA){
      a1r = *(const float4*)(A1 + (size_t)(m0+arow)*DM + c0 + ac4);
      if (DUAL) a2r = *(const float4*)(A2 + (size_t)(m0+arow)*DM + c0 + ac4);
    }
  };

  float acc[8][NQ];
  #pragma unroll
  for (int r=0;r<8;r++)
    #pragma unroll
    for (int q=0;q<NQ;q++) acc[r][q] = 0.f;

  load_chunk(0);

  for (int c0=0; c0<DM; c0+=KC){
    __syncthreads();                       // prior compute done reading LDS
    *(float4*)&Wl1[wrow0*WS + wc40] = w1r0;
    *(float4*)&Wl1[wrow1*WS + wc41] = w1r1;
    if (DUAL){
      *(float4*)&Wl2[wrow0*WS + wc40] = w2r0;
      *(float4*)&Wl2[wrow1*WS + wc41] = w2r1;
    }
    if (hasA){
      *(float4*)&Al1[arow*KC + ac4] = a1r;
      if (DUAL) *(float4*)&Al2[arow*KC + ac4] = a2r;
    }
    __syncthreads();
    if (c0 + KC < DM) load_chunk(c0 + KC); // prefetch next chunk under compute

    #pragma unroll
    for (int k4=0; k4<KC/4; k4++){
      float4 wv1[NQ]; float4 wv2[NQ];
      #pragma unroll
      for (int q=0;q<NQ;q++){
        wv1[q] = *(const float4*)&Wl1[(cg+64*q)*WS + k4*4];
        if (DUAL) wv2[q] = *(const float4*)&Wl2[(cg+64*q)*WS + k4*4];
      }
      #pragma unroll
      for (int r=0;r<8;r++){
        float4 a1 = *(const float4*)&Al1[(rg*8+r)*KC + k4*4];   // wave-uniform broadcast
        float4 a2;
        if (DUAL) a2 = *(const float4*)&Al2[(rg*8+r)*KC + k4*4];
        #pragma unroll
        for (int q=0;q<NQ;q++){
          float s = acc[r][q];
          s = fmaf(a1.x, wv1[q].x, s);
          s = fmaf(a1.y, wv1[q].y, s);
          s = fmaf(a1.z, wv1[q].z, s);
          s = fmaf(a1.w, wv1[q].w, s);
          if (DUAL){
            s = fmaf(a2.x, wv2[q].x, s);
            s = fmaf(a2.y, wv2[q].y, s);
            s = fmaf(a2.z, wv2[q].z, s);
            s = fmaf(a2.w, wv2[q].w, s);
          }
          acc[r][q] = s;
        }
      }
    }
  }
  #pragma unroll
  for (int q=0;q<NQ;q++){
    int d = colbase + cg + 64*q;
    float bv = BIAS ? bias[d] : 0.f;
    #pragma unroll
    for (int r=0;r<8;r++){
      float v = geluf(acc[r][q] + bv);
      C[(size_t)(m0 + rg*8 + r)*OUT + d] = v;
    }
  }
}

// ---------------- weighted neighbor aggregation ----------------
__global__ __launch_bounds__(256) void agg_kernel_r17(const float* __restrict__ h,
    const int* __restrict__ idx, const float* __restrict__ w, float* __restrict__ agg)
{
  const int lane = threadIdx.x & 63, wid = threadIdx.x >> 6;
  const int n = blockIdx.x*4 + wid;
  const int base = n*KNN;
  float4 acc = make_float4(0.f,0.f,0.f,0.f);
  for (int k=0;k<KNN;k++){
    int j = idx[base+k];
    float wk = w[base+k];
    float4 hv = *(const float4*)(h + (size_t)j*DM + lane*4);
    acc.x = fmaf(wk, hv.x, acc.x);
    acc.y = fmaf(wk, hv.y, acc.y);
    acc.z = fmaf(wk, hv.z, acc.z);
    acc.w = fmaf(wk, hv.w, acc.w);
  }
  *(float4*)(agg + (size_t)n*DM + lane*4) = acc;
}

// ---------------- h = h + layernorm(tmp)*g + b ----------------
__global__ __launch_bounds__(256) void ln_res_kernel_r17(float* __restrict__ h,
    const float* __restrict__ tmp, const float* __restrict__ g, const float* __restrict__ b)
{
  const int lane = threadIdx.x & 63, wid = threadIdx.x >> 6;
  const int n = blockIdx.x*4 + wid;
  float4 x = *(const float4*)(tmp + (size_t)n*DM + lane*4);
  float s = (x.x + x.y) + (x.z + x.w);
  #pragma unroll
  for (int off=32; off>0; off>>=1) s += __shfl_xor(s, off, 64);
  float mu = s * (1.0f/DM);
  float dx0 = x.x-mu, dx1 = x.y-mu, dx2 = x.z-mu, dx3 = x.w-mu;
  float v = (dx0*dx0 + dx1*dx1) + (dx2*dx2 + dx3*dx3);
  #pragma unroll
  for (int off=32; off>0; off>>=1) v += __shfl_xor(v, off, 64);
  float rs = 1.0f / sqrtf(v * (1.0f/DM) + 1e-5f);
  int c = lane*4;
  float4 gv = *(const float4*)(g + c);
  float4 bv = *(const float4*)(b + c);
  float4 hv = *(const float4*)(h + (size_t)n*DM + c);
  hv.x += dx0*rs*gv.x + bv.x;
  hv.y += dx1*rs*gv.y + bv.y;
  hv.z += dx2*rs*gv.z + bv.z;
  hv.w += dx3*rs*gv.w + bv.w;
  *(float4*)(h + (size_t)n*DM + c) = hv;
}

// ---------------- final: out[n] = sigmoid(dot(hid[n], w2) + b2), dtype per flag ----------------
__global__ __launch_bounds__(256) void cls2_kernel_r17(const float* __restrict__ hid,
    const float* __restrict__ w2, const float* __restrict__ b2,
    void* __restrict__ out, const int* __restrict__ flag)
{
  const int lane = threadIdx.x & 63, wid = threadIdx.x >> 6;
  const int n = blockIdx.x*4 + wid;
  float a = hid[(size_t)n*128 + lane]      * w2[lane]
          + hid[(size_t)n*128 + 64 + lane] * w2[64+lane];
  #pragma unroll
  for (int off=32; off>0; off>>=1) a += __shfl_xor(a, off, 64);
  if (lane == 0){
    float v = 1.0f / (1.0f + expf(-(a + b2[0])));
    if (*flag) ((__hip_bfloat16*)out)[n] = __float2bfloat16(v);
    else       ((float*)out)[n] = v;
  }
}

extern "C" void kernel_launch(void* const* d_in, const int* in_sizes, int n_in,
                              void* d_out, int out_size, void* d_ws, size_t ws_size,
                              hipStream_t stream)
{
  // ---- workspace layout (~45 MB), fully rewritten every call ----
  char* base = (char*)d_ws;
  int*   flag = (int*)base;                                   // 16 B slot
  float* wreg = (float*)(base + 16);
  static const int sizes[16] = {
    NND*256, NND*2, 256*256, 256, 256*256, 256*256, 256, 256,
    256*256, 256*256, 256, 256, 128*256, 128, 128, 1
  };
  float* ptrs[16];
  {
    float* p = wreg;
    for (int i = 2; i < 16; i++){ ptrs[i] = p; p += sizes[i]; }
    ptrs[1] = p;                          // cents  [24,000]
    p += NND*2;
    ptrs[0] = p;                          // feats  [3,072,000]  (reused as tmp later)
  }
  float* F    = ptrs[0];
  float* C    = ptrs[1];
  float* h    = F + (size_t)NND*DM;
  float* agg  = h + (size_t)NND*DM;
  float* hid  = agg + (size_t)NND*DM;
  int*  gidx  = (int*)(hid + (size_t)NND*128);
  float* gw   = (float*)(gidx + (size_t)NND*KNN);
  // knn pre-pass scratch
  float2* sxy   = (float2*)(gw + (size_t)NND*KNN);
  int*    sid   = (int*)(sxy + NND);
  int*    hist  = sid + NND;
  int*    cursor= hist + NB;
  int*    offs  = cursor + NB;
  int*    ocnt  = offs + NB;
  int*    olist = ocnt + 1;               // up to 12000 ints
  float*  othr  = (float*)(olist + NND);  // thr per deferred node

  // ---- dtype detect + decode ----
  detect_kernel_r17<<<1, 256, 0, stream>>>((const unsigned*)d_in[1], 4096,
                                           (const unsigned*)d_in[0], 16384, flag);
  SegTable t;
  int total = 0;
  for (int i = 0; i < 16; i++){
    t.src[i] = d_in[i];
    t.dst[i] = ptrs[i];
    t.cnt[i] = sizes[i];
    total += sizes[i];
  }
  t.total = total;
  decode_kernel_r17<<<(total + 255)/256, 256, 0, stream>>>(t, flag);

  const float* enc_w  = ptrs[2];  const float* enc_b  = ptrs[3];
  const float* g1_ws  = ptrs[4];  const float* g1_wn  = ptrs[5];
  const float* g1_g   = ptrs[6];  const float* g1_b   = ptrs[7];
  const float* g2_ws  = ptrs[8];  const float* g2_wn  = ptrs[9];
  const float* g2_g   = ptrs[10]; const float* g2_b   = ptrs[11];
  const float* cls_w1 = ptrs[12]; const float* cls_b1 = ptrs[13];
  const float* cls_w2 = ptrs[14]; const float* cls_b2 = ptrs[15];

  dim3 b256(256);
  // knn pre-pass: bucket counting sort by x (+ zero outlier counter)
  zero_kernel_r17<<<(NB + 255)/256, b256, 0, stream>>>(hist, cursor, ocnt);
  count_kernel_r17<<<(NND + 255)/256, b256, 0, stream>>>(C, hist);
  scan_kernel_r17<<<1, 1024, 0, stream>>>(hist, offs);
  scatter_kernel_r17<<<(NND + 255)/256, b256, 0, stream>>>(C, offs, cursor, sxy, sid);
  // encoder: h = gelu(feats @ enc_w^T + enc_b)
  mm_kernel_r17<256,128,false,true><<<dim3(NND/32, 2), b256, 0, stream>>>(F, nullptr, enc_w, nullptr, enc_b, h);
  // knn: fixed-window wave-per-node + bounded rescan for deferred nodes
  knn_fixed_r17<<<NND/4, b256, 0, stream>>>(sxy, sid, C, offs, gidx, gw, ocnt, olist, othr);
  knn_ext_r17<<<512, b256, 0, stream>>>(sxy, sid, C, offs, olist, othr, ocnt, gidx, gw);
  // sage layer 1 (tmp := F, feats dead after encoder)
  agg_kernel_r17<<<NND/4, b256, 0, stream>>>(h, gidx, gw, agg);
  mm_kernel_r17<256,128,true,false><<<dim3(NND/32, 2), b256, 0, stream>>>(h, agg, g1_ws, g1_wn, nullptr, F);
  ln_res_kernel_r17<<<NND/4, b256, 0, stream>>>(h, F, g1_g, g1_b);
  // sage layer 2
  agg_kernel_r17<<<NND/4, b256, 0, stream>>>(h, gidx, gw, agg);
  mm_kernel_r17<256,128,true,false><<<dim3(NND/32, 2), b256, 0, stream>>>(h, agg, g2_ws, g2_wn, nullptr, F);
  ln_res_kernel_r17<<<NND/4, b256, 0, stream>>>(h, F, g2_g, g2_b);
  // classifier
  mm_kernel_r17<128,128,false,true><<<dim3(NND/32, 1), b256, 0, stream>>>(h, nullptr, cls_w1, nullptr, cls_b1, hid);
  cls2_kernel_r17<<<NND/4, b256, 0, stream>>>(hid, cls_w2, cls_b2, d_out, flag);
}

// Round 18
// 500.159 us; speedup vs baseline: 1.8037x; 1.0462x over previous
//
#include <hip/hip_runtime.h>
#include <hip/hip_bf16.h>
#include <stdint.h>

#define NND 12000
#define DM  256
#define KNN 16
#define NB  4096          // x-buckets
#define BW  0.00390625f   // bucket width = 1/256 over [-8, 8)
#define RW  16            // fixed-window rounds (16*64 = 1024 candidates)
#define NWELEM 360448     // total weight elements converted to bf16 hi/lo

// Opaque register barrier: prevents FMA contraction (r9: made knn bit-match numpy
// -> absmax 0.0. DO NOT REMOVE from knn path).
#define FPBAR(x) asm volatile("" : "+v"(x))

typedef unsigned long long u64;
typedef __attribute__((ext_vector_type(8))) short bf8_t;   // 8 bf16 (4 VGPRs)
typedef __attribute__((ext_vector_type(4))) float f4_t;

__device__ __forceinline__ float geluf(float x){ return 0.5f*x*(1.0f + erff(x*0.70710678118654752f)); }
__device__ __forceinline__ int bucketof(float x){
  int b = (int)floorf((x + 8.0f) * 256.0f);
  return min(max(b, 0), NB-1);
}

__device__ __forceinline__ unsigned short bf16_rne(float x){
  unsigned u = __float_as_uint(x);
  unsigned r = u + 0x7FFF + ((u >> 16) & 1);
  return (unsigned short)(r >> 16);
}

// split 8 floats into hi/lo bf16 fragments (x = hi + lo up to ~2^-17 rel)
__device__ __forceinline__ void split8(const float4& v0, const float4& v1,
                                       bf8_t& h, bf8_t& l){
  float xs[8] = {v0.x,v0.y,v0.z,v0.w,v1.x,v1.y,v1.z,v1.w};
  #pragma unroll
  for (int i=0;i<8;i++){
    unsigned short hb = bf16_rne(xs[i]);
    float hf = __uint_as_float(((unsigned)hb) << 16);
    unsigned short lb = bf16_rne(xs[i] - hf);
    h[i] = (short)hb;
    l[i] = (short)lb;
  }
}

// bit-exact numpy distance key (r9-verified). Low 32 bits = original node idx.
__device__ __forceinline__ u64 make_key(float xi, float yi, float sqi,
                                        float cx, float cy, int jd, int self){
  float ax = cx*cx;  FPBAR(ax);
  float ay = cy*cy;  FPBAR(ay);
  float sqj = ax + ay;   FPBAR(sqj);
  float px = xi*cx;    FPBAR(px);
  float py = yi*cy;    FPBAR(py);
  float dt = px + py;    FPBAR(dt);            // NO-FMA dot
  float two_dt = 2.0f*dt;  FPBAR(two_dt);
  float ss = sqi + sqj;    FPBAR(ss);
  float d2 = ss - two_dt;  FPBAR(d2);
  float dist = __fsqrt_rn(fmaxf(d2, 0.0f));
  u64 key = ((u64)__float_as_uint(dist) << 32) | (unsigned)jd;
  return (jd == self) ? ~0ULL : key;
}

__device__ __forceinline__ void ladder_insert(u64* L, u64 key){
  bool c[KNN];
  #pragma unroll
  for (int t=0;t<KNN;t++) c[t] = key < L[t];
  #pragma unroll
  for (int t=KNN-1;t>=1;t--) L[t] = c[t-1] ? L[t-1] : (c[t] ? key : L[t]);
  L[0] = c[0] ? key : L[0];
}

__device__ __forceinline__ u64 wave_merge16(u64* slice, int lane, const u64* L)
{
  #pragma unroll
  for (int t=0;t<KNN;t++) slice[t*64 + lane] = L[t];
  int p = 0;
  u64 cur = slice[lane];
  u64 out16 = ~0ULL;
  for (int r=0;r<KNN;r++){
    u64 k = cur; int who = lane;
    #pragma unroll
    for (int o=32;o>0;o>>=1){
      u64 ok = __shfl_xor(k, o, 64);
      int ow = __shfl_xor(who, o, 64);
      if (ok < k){ k = ok; who = ow; }
    }
    if (lane == r) out16 = k;
    if (lane == who){
      ++p;
      cur = (p < KNN) ? slice[p*64 + lane] : ~0ULL;
    }
  }
  return out16;
}

__device__ __forceinline__ void write_outputs(u64 out16, int lane, int n,
    int* __restrict__ idx_out, float* __restrict__ w_out)
{
  if (lane < KNN) idx_out[(size_t)n*KNN + lane] = (int)(unsigned)(out16 & 0xFFFFFFFFull);
  u64 kt[KNN];
  #pragma unroll
  for (int t=0;t<KNN;t++) kt[t] = __shfl(out16, t, 64);
  float inv[KNN];
  #pragma unroll
  for (int t=0;t<KNN;t++){
    float d = __uint_as_float((unsigned)(kt[t] >> 32));
    inv[t] = __fdiv_rn(1.0f, fmaxf(d, 1e-4f));
  }
  float r8v[8];
  #pragma unroll
  for (int t=0;t<8;t++){ r8v[t] = inv[t] + inv[t+8]; FPBAR(r8v[t]); }
  float s01 = r8v[0]+r8v[1]; FPBAR(s01);
  float s23 = r8v[2]+r8v[3]; FPBAR(s23);
  float s45 = r8v[4]+r8v[5]; FPBAR(s45);
  float s67 = r8v[6]+r8v[7]; FPBAR(s67);
  float sA = s01+s23; FPBAR(sA);
  float sB = s45+s67; FPBAR(sB);
  float s = sA + sB;
  s = fmaxf(s, 1e-8f);
  if (lane < KNN){
    float d = __uint_as_float((unsigned)(out16 >> 32));
    float invL = __fdiv_rn(1.0f, fmaxf(d, 1e-4f));
    w_out[(size_t)n*KNN + lane] = __fdiv_rn(invL, s);
  }
}

// ---------------- dtype detection (proven: picks f32 here) ----------------
__global__ __launch_bounds__(256) void detect_kernel_r18(
    const unsigned* __restrict__ a, int na,
    const unsigned* __restrict__ b, int nb, int* __restrict__ flag)
{
  __shared__ int cnt;
  if (threadIdx.x == 0) cnt = 0;
  __syncthreads();
  int c = 0;
  for (int i = threadIdx.x; i < na; i += 256){
    int ex = (a[i] >> 7) & 0xFF;
    c += (ex >= 113 && ex <= 131) ? 1 : 0;
  }
  for (int i = threadIdx.x; i < nb; i += 256){
    int ex = (b[i] >> 7) & 0xFF;
    c += (ex >= 113 && ex <= 131) ? 1 : 0;
  }
  atomicAdd(&cnt, c);
  __syncthreads();
  if (threadIdx.x == 0) *flag = (cnt > (na + nb) / 2) ? 1 : 0;
}

// ---------------- decode all inputs to f32 workspace ----------------
struct SegTable {
  const void* src[16];
  float*      dst[16];
  int         cnt[16];
  int         total;
};

__global__ __launch_bounds__(256) void decode_kernel_r18(SegTable t, const int* __restrict__ flag)
{
  const int is_bf16 = *flag;
  for (int e = blockIdx.x*256 + threadIdx.x; e < t.total; e += gridDim.x*256){
    int rem = e, s = 0;
    while (rem >= t.cnt[s]){ rem -= t.cnt[s]; ++s; }
    float v;
    if (is_bf16) v = __uint_as_float(((unsigned)((const unsigned short*)t.src[s])[rem]) << 16);
    else         v = ((const float*)t.src[s])[rem];
    t.dst[s][rem] = v;
  }
}

// ---------------- weight pre-convert: fp32 -> bf16 hi/lo (once per launch) ----------------
struct WcTable { const float* src[6]; int cnt[6]; };

__global__ __launch_bounds__(256) void wconv_r18(WcTable t,
    unsigned short* __restrict__ dh, unsigned short* __restrict__ dl)
{
  for (int e = blockIdx.x*256 + threadIdx.x; e < NWELEM; e += gridDim.x*256){
    int rem = e, s = 0;
    while (rem >= t.cnt[s]){ rem -= t.cnt[s]; ++s; }
    float x = t.src[s][rem];
    unsigned short hb = bf16_rne(x);
    float hf = __uint_as_float(((unsigned)hb) << 16);
    dh[e] = hb;
    dl[e] = bf16_rne(x - hf);
  }
}

// ---------------- bucket pre-pass ----------------
__global__ __launch_bounds__(256) void zero_kernel_r18(int* __restrict__ hist, int* __restrict__ cursor,
                                                       int* __restrict__ ocnt)
{
  int t = blockIdx.x*256 + threadIdx.x;
  if (t < NB){ hist[t] = 0; cursor[t] = 0; }
  if (blockIdx.x == 0 && threadIdx.x == 0) *ocnt = 0;
}

__global__ __launch_bounds__(256) void count_kernel_r18(const float* __restrict__ cents,
                                                        int* __restrict__ hist)
{
  int i = blockIdx.x*256 + threadIdx.x;
  if (i < NND) atomicAdd(&hist[bucketof(cents[2*i])], 1);
}

__global__ __launch_bounds__(1024) void scan_kernel_r18(const int* __restrict__ hist,
                                                        int* __restrict__ offs)
{
  __shared__ int s[1024];
  int t = threadIdx.x;
  int h0 = hist[t*4], h1 = hist[t*4+1], h2 = hist[t*4+2], h3 = hist[t*4+3];
  int tot = h0+h1+h2+h3;
  s[t] = tot;
  __syncthreads();
  for (int d=1; d<1024; d<<=1){
    int v = (t >= d) ? s[t-d] : 0;
    __syncthreads();
    s[t] += v;
    __syncthreads();
  }
  int excl = s[t] - tot;
  offs[t*4]   = excl;
  offs[t*4+1] = excl + h0;
  offs[t*4+2] = excl + h0 + h1;
  offs[t*4+3] = excl + h0 + h1 + h2;
}

__global__ __launch_bounds__(256) void scatter_kernel_r18(const float* __restrict__ cents,
    const int* __restrict__ offs, int* __restrict__ cursor,
    float2* __restrict__ sxy, int* __restrict__ sid)
{
  int i = blockIdx.x*256 + threadIdx.x;
  if (i < NND){
    float x = cents[2*i], y = cents[2*i+1];
    int b = bucketof(x);
    int pos = offs[b] + atomicAdd(&cursor[b], 1);
    sxy[pos] = make_float2(x, y);
    sid[pos] = i;
  }
}

// ---------------- kNN: fixed 1024-window per node + post-hoc check (r15-verified, bit-exact) ----------------
__global__ __launch_bounds__(256) void knn_fixed_r18(
    const float2* __restrict__ sxy, const int* __restrict__ sid,
    const float* __restrict__ cents, const int* __restrict__ offs,
    int* __restrict__ idx_out, float* __restrict__ w_out,
    int* __restrict__ ocnt, int* __restrict__ olist, float* __restrict__ othr)
{
  __shared__ u64 lds_k[4][KNN*64];   // 32 KB
  const int lane = threadIdx.x & 63, wv = threadIdx.x >> 6;
  const int n = blockIdx.x*4 + wv;
  const float xi = cents[2*n];
  const float yi = cents[2*n+1];
  float sx = xi*xi; FPBAR(sx);
  float sy = yi*yi; FPBAR(sy);
  float sqi = sx + sy; FPBAR(sqi);

  const int start = offs[bucketof(xi)];
  const bool isR = lane < 32;
  const int lo = isR ? lane : (lane - 32);

  u64 L[KNN];
  #pragma unroll
  for (int t=0;t<KNN;t++) L[t] = ~0ULL;

  #pragma unroll 2
  for (int r=0;r<RW;r++){
    int myp = isR ? (start + r*32 + lo) : (start - 1 - r*32 - lo);
    bool act = (myp >= 0) && (myp < NND);
    float2 cu = make_float2(0.f, 0.f);
    int jd = -1;
    if (act){ cu = sxy[myp]; jd = sid[myp]; }
    u64 key = make_key(xi, yi, sqi, cu.x, cu.y, jd, n);
    if (!act) key = ~0ULL;
    ladder_insert(L, key);
  }

  u64 out16 = wave_merge16(&lds_k[wv][0], lane, L);
  float B = __uint_as_float((unsigned)(__shfl(out16, KNN-1, 64) >> 32));
  const float thr = B*B + 2e-4f;

  const int qr = min(start + RW*32, NND);
  const int ql = max(start - RW*32, 0);
  bool ok;
  {
    bool rok = (qr >= NND);
    if (!rok){
      float xR = sxy[qr-1].x;
      float dxr = ((float)bucketof(xR)*BW - 8.0f) - xi;
      rok = (dxr > 0.0f) && (dxr*dxr > thr);
    }
    bool lok = (ql <= 0);
    if (!lok){
      float xL = sxy[ql].x;
      float dxl = xi - ((float)(bucketof(xL)+1)*BW - 8.0f);
      lok = (dxl > 0.0f) && (dxl*dxl > thr);
    }
    ok = rok && lok;
  }
  if (lane == 0 && !ok){
    int s = atomicAdd(ocnt, 1);
    olist[s] = n;
    othr[s] = thr;
  }

  write_outputs(out16, lane, n, idx_out, w_out);
}

// ---------------- bounded rescan for deferred nodes (r15-verified, exact) ----------------
__global__ __launch_bounds__(256) void knn_ext_r18(
    const float2* __restrict__ sxy, const int* __restrict__ sid,
    const float* __restrict__ cents, const int* __restrict__ offs,
    const int* __restrict__ olist, const float* __restrict__ othr,
    const int* __restrict__ ocnt,
    int* __restrict__ idx_out, float* __restrict__ w_out)
{
  __shared__ u64 lds_k[4][KNN*64];   // 32 KB
  const int lane = threadIdx.x & 63, wv = threadIdx.x >> 6;
  const int cnt = *ocnt;

  for (int slot = blockIdx.x*4 + wv; slot < cnt; slot += gridDim.x*4){
    const int n = olist[slot];
    const float thr = othr[slot];
    const float rB = __fsqrt_rn(thr) * (1.0f + 2e-6f);
    const float xi = cents[2*n];
    const float yi = cents[2*n+1];
    float sx = xi*xi; FPBAR(sx);
    float sy = yi*yi; FPBAR(sy);
    float sqi = sx + sy; FPBAR(sqi);

    const int bL = bucketof(xi - rB);
    const int bR = bucketof(xi + rB);
    const int posL = offs[bL];
    const int posR = (bR + 1 < NB) ? offs[bR + 1] : NND;

    u64 L[KNN];
    #pragma unroll
    for (int t=0;t<KNN;t++) L[t] = ~0ULL;

    for (int p = posL + lane; p < posR; p += 64){
      float2 cu = sxy[p];
      ladder_insert(L, make_key(xi, yi, sqi, cu.x, cu.y, sid[p], n));
    }

    u64 out16 = wave_merge16(&lds_k[wv][0], lane, L);
    write_outputs(out16, lane, n, idx_out, w_out);
  }
}

// ---------------- GEMM via bf16 MFMA with hi/lo split ----------------
// C[M,OUT] = gelu(A1@W1^T (+ A2@W2^T) (+ bias)); A fp32 split in-register into
// hi/lo bf16; W pre-split by wconv_r18. Per k-tile: AhBh + AhBl + AlBh (drop AlBl,
// rel err ~2^-16; sigmoid-output error ~1e-4 << 1.875e-2 threshold).
// mfma_f32_16x16x32_bf16 layouts (guide-verified): A[m=lane&15][k=quad*8+j],
// B[k=quad*8+j][n=lane&15], C/D col=lane&15 row=quad*4+reg.
// Wave job = 16 rows x 64 cols (4 tiles); 4 waves/block share A rows (L1 hit).
// No LDS, no barriers.
template<int OUT, bool DUAL, bool BIAS>
__global__ __launch_bounds__(256) void mm_mfma_r18(
    const float* __restrict__ A1, const float* __restrict__ A2,
    const unsigned short* __restrict__ W1h, const unsigned short* __restrict__ W1l,
    const unsigned short* __restrict__ W2h, const unsigned short* __restrict__ W2l,
    const float* __restrict__ bias, float* __restrict__ C, int njobs)
{
  constexpr int NCG = OUT / 64;
  const int lane = threadIdx.x & 63, wv = threadIdx.x >> 6;
  const int job = blockIdx.x*4 + wv;
  if (job >= njobs) return;
  const int rowtile = job / NCG;
  const int cg = job % NCG;
  const int l15 = lane & 15;
  const int quad = lane >> 4;
  const int m = rowtile*16 + l15;       // A-operand row for this lane
  const int n0 = cg*64;
  const int nb = n0 + l15;              // B-operand col base (tile t adds t*16)

  f4_t acc[4];
  #pragma unroll
  for (int t=0;t<4;t++) acc[t] = (f4_t){0.f,0.f,0.f,0.f};

  for (int k0=0; k0<DM; k0+=32){
    const int kq = k0 + quad*8;
    bf8_t a1h, a1l, a2h, a2l;
    {
      float4 v0 = *(const float4*)(A1 + (size_t)m*DM + kq);
      float4 v1 = *(const float4*)(A1 + (size_t)m*DM + kq + 4);
      split8(v0, v1, a1h, a1l);
      if (DUAL){
        float4 u0 = *(const float4*)(A2 + (size_t)m*DM + kq);
        float4 u1 = *(const float4*)(A2 + (size_t)m*DM + kq + 4);
        split8(u0, u1, a2h, a2l);
      }
    }
    #pragma unroll
    for (int t=0;t<4;t++){
      size_t wo = (size_t)(nb + t*16)*DM + kq;
      bf8_t bh = *(const bf8_t*)(W1h + wo);
      bf8_t bl = *(const bf8_t*)(W1l + wo);
      acc[t] = __builtin_amdgcn_mfma_f32_16x16x32_bf16(a1h, bh, acc[t], 0, 0, 0);
      acc[t] = __builtin_amdgcn_mfma_f32_16x16x32_bf16(a1h, bl, acc[t], 0, 0, 0);
      acc[t] = __builtin_amdgcn_mfma_f32_16x16x32_bf16(a1l, bh, acc[t], 0, 0, 0);
      if (DUAL){
        bf8_t ch = *(const bf8_t*)(W2h + wo);
        bf8_t cl = *(const bf8_t*)(W2l + wo);
        acc[t] = __builtin_amdgcn_mfma_f32_16x16x32_bf16(a2h, ch, acc[t], 0, 0, 0);
        acc[t] = __builtin_amdgcn_mfma_f32_16x16x32_bf16(a2h, cl, acc[t], 0, 0, 0);
        acc[t] = __builtin_amdgcn_mfma_f32_16x16x32_bf16(a2l, ch, acc[t], 0, 0, 0);
      }
    }
  }

  #pragma unroll
  for (int t=0;t<4;t++){
    int n = n0 + t*16 + l15;
    float bv = BIAS ? bias[n] : 0.f;
    #pragma unroll
    for (int r=0;r<4;r++){
      int row = rowtile*16 + quad*4 + r;
      C[(size_t)row*OUT + n] = geluf(acc[t][r] + bv);
    }
  }
}

// ---------------- weighted neighbor aggregation ----------------
__global__ __launch_bounds__(256) void agg_kernel_r18(const float* __restrict__ h,
    const int* __restrict__ idx, const float* __restrict__ w, float* __restrict__ agg)
{
  const int lane = threadIdx.x & 63, wid = threadIdx.x >> 6;
  const int n = blockIdx.x*4 + wid;
  const int base = n*KNN;
  float4 acc = make_float4(0.f,0.f,0.f,0.f);
  for (int k=0;k<KNN;k++){
    int j = idx[base+k];
    float wk = w[base+k];
    float4 hv = *(const float4*)(h + (size_t)j*DM + lane*4);
    acc.x = fmaf(wk, hv.x, acc.x);
    acc.y = fmaf(wk, hv.y, acc.y);
    acc.z = fmaf(wk, hv.z, acc.z);
    acc.w = fmaf(wk, hv.w, acc.w);
  }
  *(float4*)(agg + (size_t)n*DM + lane*4) = acc;
}

// ---------------- h = h + layernorm(tmp)*g + b ----------------
__global__ __launch_bounds__(256) void ln_res_kernel_r18(float* __restrict__ h,
    const float* __restrict__ tmp, const float* __restrict__ g, const float* __restrict__ b)
{
  const int lane = threadIdx.x & 63, wid = threadIdx.x >> 6;
  const int n = blockIdx.x*4 + wid;
  float4 x = *(const float4*)(tmp + (size_t)n*DM + lane*4);
  float s = (x.x + x.y) + (x.z + x.w);
  #pragma unroll
  for (int off=32; off>0; off>>=1) s += __shfl_xor(s, off, 64);
  float mu = s * (1.0f/DM);
  float dx0 = x.x-mu, dx1 = x.y-mu, dx2 = x.z-mu, dx3 = x.w-mu;
  float v = (dx0*dx0 + dx1*dx1) + (dx2*dx2 + dx3*dx3);
  #pragma unroll
  for (int off=32; off>0; off>>=1) v += __shfl_xor(v, off, 64);
  float rs = 1.0f / sqrtf(v * (1.0f/DM) + 1e-5f);
  int c = lane*4;
  float4 gv = *(const float4*)(g + c);
  float4 bv = *(const float4*)(b + c);
  float4 hv = *(const float4*)(h + (size_t)n*DM + c);
  hv.x += dx0*rs*gv.x + bv.x;
  hv.y += dx1*rs*gv.y + bv.y;
  hv.z += dx2*rs*gv.z + bv.z;
  hv.w += dx3*rs*gv.w + bv.w;
  *(float4*)(h + (size_t)n*DM + c) = hv;
}

// ---------------- final: out[n] = sigmoid(dot(hid[n], w2) + b2), dtype per flag ----------------
__global__ __launch_bounds__(256) void cls2_kernel_r18(const float* __restrict__ hid,
    const float* __restrict__ w2, const float* __restrict__ b2,
    void* __restrict__ out, const int* __restrict__ flag)
{
  const int lane = threadIdx.x & 63, wid = threadIdx.x >> 6;
  const int n = blockIdx.x*4 + wid;
  float a = hid[(size_t)n*128 + lane]      * w2[lane]
          + hid[(size_t)n*128 + 64 + lane] * w2[64+lane];
  #pragma unroll
  for (int off=32; off>0; off>>=1) a += __shfl_xor(a, off, 64);
  if (lane == 0){
    float v = 1.0f / (1.0f + expf(-(a + b2[0])));
    if (*flag) ((__hip_bfloat16*)out)[n] = __float2bfloat16(v);
    else       ((float*)out)[n] = v;
  }
}

extern "C" void kernel_launch(void* const* d_in, const int* in_sizes, int n_in,
                              void* d_out, int out_size, void* d_ws, size_t ws_size,
                              hipStream_t stream)
{
  // ---- workspace layout (~46.5 MB), fully rewritten every call ----
  char* base = (char*)d_ws;
  int*   flag = (int*)base;                                   // 16 B slot
  float* wreg = (float*)(base + 16);
  static const int sizes[16] = {
    NND*256, NND*2, 256*256, 256, 256*256, 256*256, 256, 256,
    256*256, 256*256, 256, 256, 128*256, 128, 128, 1
  };
  float* ptrs[16];
  {
    float* p = wreg;
    for (int i = 2; i < 16; i++){ ptrs[i] = p; p += sizes[i]; }
    ptrs[1] = p;                          // cents  [24,000]
    p += NND*2;
    ptrs[0] = p;                          // feats  [3,072,000]  (reused as tmp later)
  }
  float* F    = ptrs[0];
  float* C    = ptrs[1];
  float* h    = F + (size_t)NND*DM;
  float* agg  = h + (size_t)NND*DM;
  float* hid  = agg + (size_t)NND*DM;
  int*  gidx  = (int*)(hid + (size_t)NND*128);
  float* gw   = (float*)(gidx + (size_t)NND*KNN);
  // knn pre-pass scratch
  float2* sxy   = (float2*)(gw + (size_t)NND*KNN);
  int*    sid   = (int*)(sxy + NND);
  int*    hist  = sid + NND;
  int*    cursor= hist + NB;
  int*    offs  = cursor + NB;
  int*    ocnt  = offs + NB;
  int*    olist = ocnt + 1;               // up to 12000 ints
  float*  othr  = (float*)(olist + NND);  // thr per deferred node
  // bf16 hi/lo weights (enc_w | g1_ws | g1_wn | g2_ws | g2_wn | cls_w1)
  unsigned short* wh = (unsigned short*)(othr + NND);
  unsigned short* wl = wh + NWELEM;

  // ---- dtype detect + decode ----
  detect_kernel_r18<<<1, 256, 0, stream>>>((const unsigned*)d_in[1], 4096,
                                           (const unsigned*)d_in[0], 16384, flag);
  SegTable t;
  int total = 0;
  for (int i = 0; i < 16; i++){
    t.src[i] = d_in[i];
    t.dst[i] = ptrs[i];
    t.cnt[i] = sizes[i];
    total += sizes[i];
  }
  t.total = total;
  decode_kernel_r18<<<(total + 255)/256, 256, 0, stream>>>(t, flag);

  const float* enc_b  = ptrs[3];
  const float* g1_g   = ptrs[6];  const float* g1_b   = ptrs[7];
  const float* g2_g   = ptrs[10]; const float* g2_b   = ptrs[11];
  const float* cls_b1 = ptrs[13];
  const float* cls_w2 = ptrs[14]; const float* cls_b2 = ptrs[15];

  // weight bf16 hi/lo conversion (after decode)
  WcTable wt;
  wt.src[0] = ptrs[2];  wt.cnt[0] = 65536;   // enc_w
  wt.src[1] = ptrs[4];  wt.cnt[1] = 65536;   // g1_ws
  wt.src[2] = ptrs[5];  wt.cnt[2] = 65536;   // g1_wn
  wt.src[3] = ptrs[8];  wt.cnt[3] = 65536;   // g2_ws
  wt.src[4] = ptrs[9];  wt.cnt[4] = 65536;   // g2_wn
  wt.src[5] = ptrs[12]; wt.cnt[5] = 32768;   // cls_w1
  wconv_r18<<<512, 256, 0, stream>>>(wt, wh, wl);

  dim3 b256(256);
  // knn pre-pass: bucket counting sort by x (+ zero outlier counter)
  zero_kernel_r18<<<(NB + 255)/256, b256, 0, stream>>>(hist, cursor, ocnt);
  count_kernel_r18<<<(NND + 255)/256, b256, 0, stream>>>(C, hist);
  scan_kernel_r18<<<1, 1024, 0, stream>>>(hist, offs);
  scatter_kernel_r18<<<(NND + 255)/256, b256, 0, stream>>>(C, offs, cursor, sxy, sid);
  // encoder: h = gelu(feats @ enc_w^T + enc_b)    [3000 wave-jobs]
  mm_mfma_r18<256,false,true><<<750, b256, 0, stream>>>(F, nullptr,
      wh + 0, wl + 0, nullptr, nullptr, enc_b, h, 3000);
  // knn: fixed-window wave-per-node + bounded rescan for deferred nodes (bit-exact)
  knn_fixed_r18<<<NND/4, b256, 0, stream>>>(sxy, sid, C, offs, gidx, gw, ocnt, olist, othr);
  knn_ext_r18<<<512, b256, 0, stream>>>(sxy, sid, C, offs, olist, othr, ocnt, gidx, gw);
  // sage layer 1 (tmp := F, feats dead after encoder)
  agg_kernel_r18<<<NND/4, b256, 0, stream>>>(h, gidx, gw, agg);
  mm_mfma_r18<256,true,false><<<750, b256, 0, stream>>>(h, agg,
      wh + 65536, wl + 65536, wh + 131072, wl + 131072, nullptr, F, 3000);
  ln_res_kernel_r18<<<NND/4, b256, 0, stream>>>(h, F, g1_g, g1_b);
  // sage layer 2
  agg_kernel_r18<<<NND/4, b256, 0, stream>>>(h, gidx, gw, agg);
  mm_mfma_r18<256,true,false><<<750, b256, 0, stream>>>(h, agg,
      wh + 196608, wl + 196608, wh + 262144, wl + 262144, nullptr, F, 3000);
  ln_res_kernel_r18<<<NND/4, b256, 0, stream>>>(h, F, g2_g, g2_b);
  // classifier [1500 wave-jobs]
  mm_mfma_r18<128,false,true><<<375, b256, 0, stream>>>(h, nullptr,
      wh + 327680, wl + 327680, nullptr, nullptr, cls_b1, hid, 1500);
  cls2_kernel_r18<<<NND/4, b256, 0, stream>>>(hid, cls_w2, cls_b2, d_out, flag);
}